// Round 4
// baseline (173.591 us; speedup 1.0000x reference)
//
#include <hip/hip_runtime.h>

typedef __bf16 bf16x8 __attribute__((ext_vector_type(8)));
typedef float f32x4 __attribute__((ext_vector_type(4)));

constexpr int SEQ = 2048;
constexpr int DMODEL = 1024;

#define GLL(gp, lp)                                                              \
  __builtin_amdgcn_global_load_lds((const __attribute__((address_space(1))) void*)(gp), \
                                   (__attribute__((address_space(3))) void*)(lp), 16, 0, 0)

// ---------------- transpose + fp32->bf16 convert: dst[C][R] = (bf16)src[R][C] ----------------
__global__ __launch_bounds__(256) void transpose_cvt(const float* __restrict__ src,
                                                     __bf16* __restrict__ dst,
                                                     int R, int C) {
  __shared__ __bf16 tile[64][72];
  int c0 = blockIdx.x * 64, r0 = blockIdx.y * 64;
  int t = threadIdx.x;
#pragma unroll
  for (int p = 0; p < 2; ++p) {
    int flat = p * 256 + t;
    int i = flat >> 3;
    int j8 = (flat & 7) * 8;
    const float* sp = &src[(size_t)(r0 + i) * C + c0 + j8];
    float4 f0 = *reinterpret_cast<const float4*>(sp);
    float4 f1 = *reinterpret_cast<const float4*>(sp + 4);
    tile[i][j8 + 0] = (__bf16)f0.x; tile[i][j8 + 1] = (__bf16)f0.y;
    tile[i][j8 + 2] = (__bf16)f0.z; tile[i][j8 + 3] = (__bf16)f0.w;
    tile[i][j8 + 4] = (__bf16)f1.x; tile[i][j8 + 5] = (__bf16)f1.y;
    tile[i][j8 + 6] = (__bf16)f1.z; tile[i][j8 + 7] = (__bf16)f1.w;
  }
  __syncthreads();
#pragma unroll
  for (int p = 0; p < 2; ++p) {
    int flat = p * 256 + t;
    int i = flat >> 3;
    int j8 = (flat & 7) * 8;
    alignas(16) __bf16 tmp[8];
#pragma unroll
    for (int jj = 0; jj < 8; ++jj) tmp[jj] = tile[j8 + jj][i];
    *reinterpret_cast<uint4*>(&dst[(size_t)(c0 + i) * R + r0 + j8]) =
        *reinterpret_cast<const uint4*>(tmp);
  }
}

// ---------------- fp32 -> bf16 bulk convert ----------------
__global__ __launch_bounds__(256) void cvt_fp32_bf16(const float* __restrict__ src,
                                                     __bf16* __restrict__ dst) {
  int i = blockIdx.x * 256 + threadIdx.x;
  const float* sp = src + (size_t)i * 8;
  float4 f0 = *reinterpret_cast<const float4*>(sp);
  float4 f1 = *reinterpret_cast<const float4*>(sp + 4);
  alignas(16) __bf16 tmp[8];
  tmp[0] = (__bf16)f0.x; tmp[1] = (__bf16)f0.y; tmp[2] = (__bf16)f0.z; tmp[3] = (__bf16)f0.w;
  tmp[4] = (__bf16)f1.x; tmp[5] = (__bf16)f1.y; tmp[6] = (__bf16)f1.z; tmp[7] = (__bf16)f1.w;
  *reinterpret_cast<uint4*>(dst + (size_t)i * 8) = *reinterpret_cast<const uint4*>(tmp);
}

// ---------------- GEMM (m97 structure): C[M][N] = A[M][K] * BT[N][K]^T ----------------
// A,BT bf16; global_load_lds width-16 staging into linear LDS; 2-barrier K-loop.
template <typename CT>
__global__ __launch_bounds__(256) void gemm_bt_lds(const __bf16* __restrict__ A,
                                                   const __bf16* __restrict__ BT,
                                                   CT* __restrict__ C,
                                                   int M, int N, int K, int lda, int ldc) {
  __shared__ __align__(16) __bf16 A_lds[128][64];
  __shared__ __align__(16) __bf16 B_lds[128][64];
  int tid = threadIdx.x;
  int lane = tid & 63, w = tid >> 6;
  int g = lane >> 4, l15 = lane & 15;
  int wr = w >> 1, wc = w & 1;
  int m0 = blockIdx.x * 128, n0 = blockIdx.y * 128;
  int srow = lane >> 3, scol = (lane & 7) * 8;

  const __bf16* ag = A + (size_t)(m0 + w * 32 + srow) * lda + scol;
  const __bf16* bg = BT + (size_t)(n0 + w * 32 + srow) * K + scol;

  f32x4 acc[4][4] = {};

  for (int k0 = 0; k0 < K; k0 += 64) {
    __syncthreads();  // previous tile's compute done
#pragma unroll
    for (int i = 0; i < 4; ++i) {
      GLL(ag + (size_t)(i * 8) * lda + k0, &A_lds[w * 32 + i * 8][0]);
      GLL(bg + (size_t)(i * 8) * K + k0, &B_lds[w * 32 + i * 8][0]);
    }
    __syncthreads();  // staging visible (compiler drains vmcnt)
#pragma unroll
    for (int kk = 0; kk < 2; ++kk) {
      bf16x8 a[4], bb[4];
#pragma unroll
      for (int m = 0; m < 4; ++m)
        a[m] = *reinterpret_cast<const bf16x8*>(&A_lds[wr * 64 + m * 16 + l15][kk * 32 + g * 8]);
#pragma unroll
      for (int n = 0; n < 4; ++n)
        bb[n] = *reinterpret_cast<const bf16x8*>(&B_lds[wc * 64 + n * 16 + l15][kk * 32 + g * 8]);
#pragma unroll
      for (int m = 0; m < 4; ++m)
#pragma unroll
        for (int n = 0; n < 4; ++n)
          acc[m][n] = __builtin_amdgcn_mfma_f32_16x16x32_bf16(a[m], bb[n], acc[m][n], 0, 0, 0);
    }
  }

#pragma unroll
  for (int m = 0; m < 4; ++m)
#pragma unroll
    for (int n = 0; n < 4; ++n)
#pragma unroll
      for (int r = 0; r < 4; ++r) {
        int row = m0 + wr * 64 + m * 16 + 4 * g + r;
        int col = n0 + wc * 64 + n * 16 + l15;
        C[(size_t)row * ldc + col] = (CT)acc[m][n][r];
      }
}

// ---------------- RoPE in-place on qkv; q additionally scaled by 0.125 (exact) ----------------
__global__ __launch_bounds__(256) void rope_kernel(__bf16* __restrict__ qkv) {
  int idx = blockIdx.x * blockDim.x + threadIdx.x;
  int d = idx & 31;
  int h = (idx >> 5) & 15;
  int qk = (idx >> 9) & 1;
  int tok = idx >> 10;
  int t = tok & (SEQ - 1);
  size_t base = (size_t)tok * 3072 + (size_t)qk * 1024 + h * 64 + d;
  float x1 = (float)qkv[base];
  float x2 = (float)qkv[base + 32];
  float theta = exp2f(-(float)d * 0.41524101186092953f);
  float ang = (float)t * theta;
  float s, c;
  __sincosf(ang, &s, &c);
  float sc = (qk == 0) ? 0.125f : 1.0f;  // fold softmax 1/sqrt(DH) into q (power of 2: exact)
  qkv[base] = (__bf16)((x1 * c - x2 * s) * sc);
  qkv[base + 32] = (__bf16)((x1 * s + x2 * c) * sc);
}

// ---------------- causal flash attention; writes y into q-slot of qkv ----------------
// 512 blocks: (bh, pair). Each block does q-tiles {31-pidx, pidx} = 33 KV-tiles total (uniform).
__global__ __launch_bounds__(256) void attn_kernel(__bf16* __restrict__ qkv) {
  __shared__ __bf16 K_lds[64][72];
  __shared__ __bf16 Vt_lds[64][72];
  __shared__ __bf16 P_lds[4][16][72];

  int tid = threadIdx.x;
  int w = tid >> 6, lane = tid & 63;
  int g = lane >> 4, l15 = lane & 15;
  int idx = blockIdx.x;
  int bh = idx & 31, pidx = idx >> 5;
  int b = bh >> 4, h = bh & 15;

  __bf16* qbase = qkv + (size_t)b * SEQ * 3072 + h * 64;
  const __bf16* kbase = qbase + 1024;
  const __bf16* vbase = qbase + 2048;

  int c8 = (tid & 7) * 8;
  int srow = tid >> 3;
  int vswz = c8;

  for (int pass = 0; pass < 2; ++pass) {
    int qb = (pass == 0) ? (31 - pidx) : pidx;
    int q_row0 = qb * 64 + w * 16;
    int q_frag_row = q_row0 + l15;

    bf16x8 qf[2];
    qf[0] = *reinterpret_cast<const bf16x8*>(qbase + (size_t)q_frag_row * 3072 + g * 8);
    qf[1] = *reinterpret_cast<const bf16x8*>(qbase + (size_t)q_frag_row * 3072 + 32 + g * 8);

    f32x4 o_acc[4] = {};
    float m_run[4], l_run[4];
#pragma unroll
    for (int r = 0; r < 4; ++r) { m_run[r] = -1e30f; l_run[r] = 0.f; }

    __syncthreads();  // all waves done with previous pass's LDS
    // stage tile 0
#pragma unroll
    for (int p = 0; p < 2; ++p) {
      int s = p * 32 + srow;
      *reinterpret_cast<uint4*>(&K_lds[s][c8]) =
          *reinterpret_cast<const uint4*>(kbase + (size_t)s * 3072 + c8);
      uint4 vv = *reinterpret_cast<const uint4*>(vbase + (size_t)s * 3072 + c8);
      const __bf16* vp = reinterpret_cast<const __bf16*>(&vv);
#pragma unroll
      for (int jj = 0; jj < 8; ++jj) Vt_lds[c8 + jj][s ^ vswz] = vp[jj];
    }
    __syncthreads();

    for (int jb = 0; jb <= qb; ++jb) {
      bool pre = (jb < qb);
      uint4 kpre[2], vpre[2];
      if (pre) {
#pragma unroll
        for (int p = 0; p < 2; ++p) {
          int s = (jb + 1) * 64 + p * 32 + srow;
          kpre[p] = *reinterpret_cast<const uint4*>(kbase + (size_t)s * 3072 + c8);
          vpre[p] = *reinterpret_cast<const uint4*>(vbase + (size_t)s * 3072 + c8);
        }
      }

      // S = Q K^T  (q pre-scaled by 0.125 in rope)
      f32x4 s_acc[4] = {};
      __builtin_amdgcn_s_setprio(1);
#pragma unroll
      for (int f = 0; f < 4; ++f) {
#pragma unroll
        for (int kk = 0; kk < 2; ++kk) {
          bf16x8 kf = *reinterpret_cast<const bf16x8*>(&K_lds[f * 16 + l15][kk * 32 + g * 8]);
          s_acc[f] = __builtin_amdgcn_mfma_f32_16x16x32_bf16(qf[kk], kf, s_acc[f], 0, 0, 0);
        }
      }
      __builtin_amdgcn_s_setprio(0);

      float pv[4][4];
      float tmax[4] = {-1e30f, -1e30f, -1e30f, -1e30f};
      if (jb == qb) {
#pragma unroll
        for (int f = 0; f < 4; ++f) {
          int s_g = jb * 64 + f * 16 + l15;
#pragma unroll
          for (int r = 0; r < 4; ++r) {
            float sv = s_acc[f][r];
            int q_g = q_row0 + 4 * g + r;
            sv = (s_g > q_g) ? -1e30f : sv;
            pv[f][r] = sv;
            tmax[r] = fmaxf(tmax[r], sv);
          }
        }
      } else {
#pragma unroll
        for (int f = 0; f < 4; ++f)
#pragma unroll
          for (int r = 0; r < 4; ++r) {
            float sv = s_acc[f][r];
            pv[f][r] = sv;
            tmax[r] = fmaxf(tmax[r], sv);
          }
      }
#pragma unroll
      for (int r = 0; r < 4; ++r) {
        float m = tmax[r];
        m = fmaxf(m, __shfl_xor(m, 1));
        m = fmaxf(m, __shfl_xor(m, 2));
        m = fmaxf(m, __shfl_xor(m, 4));
        m = fmaxf(m, __shfl_xor(m, 8));
        tmax[r] = m;
      }
      float alpha[4], rsum[4];
#pragma unroll
      for (int r = 0; r < 4; ++r) {
        float m_new = fmaxf(m_run[r], tmax[r]);
        alpha[r] = __expf(m_run[r] - m_new);
        m_run[r] = m_new;
        rsum[r] = 0.f;
      }
#pragma unroll
      for (int f = 0; f < 4; ++f) {
#pragma unroll
        for (int r = 0; r < 4; ++r) {
          float p = __expf(pv[f][r] - m_run[r]);
          rsum[r] += p;
          P_lds[w][4 * g + r][f * 16 + l15] = (__bf16)p;
        }
      }
#pragma unroll
      for (int r = 0; r < 4; ++r) {
        float s = rsum[r];
        s += __shfl_xor(s, 1);
        s += __shfl_xor(s, 2);
        s += __shfl_xor(s, 4);
        s += __shfl_xor(s, 8);
        l_run[r] = l_run[r] * alpha[r] + s;
      }
#pragma unroll
      for (int n = 0; n < 4; ++n)
#pragma unroll
        for (int r = 0; r < 4; ++r) o_acc[n][r] *= alpha[r];

      asm volatile("s_waitcnt lgkmcnt(0)" ::: "memory");
      __builtin_amdgcn_sched_barrier(0);

      // O += P V
      __builtin_amdgcn_s_setprio(1);
#pragma unroll
      for (int kk = 0; kk < 2; ++kk) {
        bf16x8 pa = *reinterpret_cast<const bf16x8*>(&P_lds[w][l15][kk * 32 + g * 8]);
#pragma unroll
        for (int n = 0; n < 4; ++n) {
          int row = n * 16 + l15;
          int col = (kk * 32 + g * 8) ^ (((row >> 3) & 7) * 8);
          bf16x8 vf = *reinterpret_cast<const bf16x8*>(&Vt_lds[row][col]);
          o_acc[n] = __builtin_amdgcn_mfma_f32_16x16x32_bf16(pa, vf, o_acc[n], 0, 0, 0);
        }
      }
      __builtin_amdgcn_s_setprio(0);

      if (pre) {
        __syncthreads();
#pragma unroll
        for (int p = 0; p < 2; ++p) {
          int s = p * 32 + srow;
          *reinterpret_cast<uint4*>(&K_lds[s][c8]) = kpre[p];
          const __bf16* vp = reinterpret_cast<const __bf16*>(&vpre[p]);
#pragma unroll
          for (int jj = 0; jj < 8; ++jj) Vt_lds[c8 + jj][s ^ vswz] = vp[jj];
        }
        __syncthreads();
      }
    }

    // epilogue: y = O / l into the q-slot (this block's exclusive rows/cols)
#pragma unroll
    for (int r = 0; r < 4; ++r) {
      float inv = 1.0f / l_run[r];
      int qrow = q_row0 + 4 * g + r;
#pragma unroll
      for (int n = 0; n < 4; ++n) {
        qbase[(size_t)qrow * 3072 + n * 16 + l15] = (__bf16)(o_acc[n][r] * inv);
      }
    }
  }
}

extern "C" void kernel_launch(void* const* d_in, const int* in_sizes, int n_in,
                              void* d_out, int out_size, void* d_ws, size_t ws_size,
                              hipStream_t stream) {
  const float* x = (const float*)d_in[0];
  const float* Wqkv = (const float*)d_in[1];
  const float* Wo = (const float*)d_in[2];
  float* out = (float*)d_out;

  __bf16* ws = (__bf16*)d_ws;
  __bf16* WqkvT = ws;                           // [3072][1024]  6 MB
  __bf16* WoT = WqkvT + 3072 * 1024;            // [1024][1024]  2 MB
  __bf16* qkv = WoT + 1024 * 1024;              // [4096][3072] 24 MB
  __bf16* xbf = qkv + (size_t)4096 * 3072;      // [4096][1024]  8 MB

  transpose_cvt<<<dim3(48, 16), 256, 0, stream>>>(Wqkv, WqkvT, 1024, 3072);
  transpose_cvt<<<dim3(16, 16), 256, 0, stream>>>(Wo, WoT, 1024, 1024);
  cvt_fp32_bf16<<<2048, 256, 0, stream>>>(x, xbf);

  gemm_bt_lds<__bf16><<<dim3(32, 24), 256, 0, stream>>>(xbf, WqkvT, qkv,
                                                        4096, 3072, 1024, 1024, 3072);
  rope_kernel<<<16384, 256, 0, stream>>>(qkv);

  attn_kernel<<<512, 256, 0, stream>>>(qkv);

  gemm_bt_lds<float><<<dim3(32, 8), 256, 0, stream>>>(qkv, WoT, out,
                                                      4096, 1024, 1024, 3072, 1024);
}

// Round 5
// 169.907 us; speedup vs baseline: 1.0217x; 1.0217x over previous
//
#include <hip/hip_runtime.h>

typedef __bf16 bf16x8 __attribute__((ext_vector_type(8)));
typedef float f32x4 __attribute__((ext_vector_type(4)));
typedef float f32x16 __attribute__((ext_vector_type(16)));

constexpr int SEQ = 2048;
constexpr int DMODEL = 1024;

#define GLL(gp, lp)                                                              \
  __builtin_amdgcn_global_load_lds((const __attribute__((address_space(1))) void*)(gp), \
                                   (__attribute__((address_space(3))) void*)(lp), 16, 0, 0)

// ---------------- transpose + fp32->bf16 convert: dst[C][R] = (bf16)src[R][C] ----------------
__global__ __launch_bounds__(256) void transpose_cvt(const float* __restrict__ src,
                                                     __bf16* __restrict__ dst,
                                                     int R, int C) {
  __shared__ __bf16 tile[64][72];
  int c0 = blockIdx.x * 64, r0 = blockIdx.y * 64;
  int t = threadIdx.x;
#pragma unroll
  for (int p = 0; p < 2; ++p) {
    int flat = p * 256 + t;
    int i = flat >> 3;
    int j8 = (flat & 7) * 8;
    const float* sp = &src[(size_t)(r0 + i) * C + c0 + j8];
    float4 f0 = *reinterpret_cast<const float4*>(sp);
    float4 f1 = *reinterpret_cast<const float4*>(sp + 4);
    tile[i][j8 + 0] = (__bf16)f0.x; tile[i][j8 + 1] = (__bf16)f0.y;
    tile[i][j8 + 2] = (__bf16)f0.z; tile[i][j8 + 3] = (__bf16)f0.w;
    tile[i][j8 + 4] = (__bf16)f1.x; tile[i][j8 + 5] = (__bf16)f1.y;
    tile[i][j8 + 6] = (__bf16)f1.z; tile[i][j8 + 7] = (__bf16)f1.w;
  }
  __syncthreads();
#pragma unroll
  for (int p = 0; p < 2; ++p) {
    int flat = p * 256 + t;
    int i = flat >> 3;
    int j8 = (flat & 7) * 8;
    alignas(16) __bf16 tmp[8];
#pragma unroll
    for (int jj = 0; jj < 8; ++jj) tmp[jj] = tile[j8 + jj][i];
    *reinterpret_cast<uint4*>(&dst[(size_t)(c0 + i) * R + r0 + j8]) =
        *reinterpret_cast<const uint4*>(tmp);
  }
}

// ---------------- fp32 -> bf16 bulk convert ----------------
__global__ __launch_bounds__(256) void cvt_fp32_bf16(const float* __restrict__ src,
                                                     __bf16* __restrict__ dst) {
  int i = blockIdx.x * 256 + threadIdx.x;
  const float* sp = src + (size_t)i * 8;
  float4 f0 = *reinterpret_cast<const float4*>(sp);
  float4 f1 = *reinterpret_cast<const float4*>(sp + 4);
  alignas(16) __bf16 tmp[8];
  tmp[0] = (__bf16)f0.x; tmp[1] = (__bf16)f0.y; tmp[2] = (__bf16)f0.z; tmp[3] = (__bf16)f0.w;
  tmp[4] = (__bf16)f1.x; tmp[5] = (__bf16)f1.y; tmp[6] = (__bf16)f1.z; tmp[7] = (__bf16)f1.w;
  *reinterpret_cast<uint4*>(dst + (size_t)i * 8) = *reinterpret_cast<const uint4*>(tmp);
}

// ---------------- GEMM (m97 structure): C[M][N] = A[M][K] * BT[N][K]^T ----------------
template <typename CT>
__global__ __launch_bounds__(256) void gemm_bt_lds(const __bf16* __restrict__ A,
                                                   const __bf16* __restrict__ BT,
                                                   CT* __restrict__ C,
                                                   int M, int N, int K, int lda, int ldc) {
  __shared__ __align__(16) __bf16 A_lds[128][64];
  __shared__ __align__(16) __bf16 B_lds[128][64];
  int tid = threadIdx.x;
  int lane = tid & 63, w = tid >> 6;
  int g = lane >> 4, l15 = lane & 15;
  int wr = w >> 1, wc = w & 1;
  int m0 = blockIdx.x * 128, n0 = blockIdx.y * 128;
  int srow = lane >> 3, scol = (lane & 7) * 8;

  const __bf16* ag = A + (size_t)(m0 + w * 32 + srow) * lda + scol;
  const __bf16* bg = BT + (size_t)(n0 + w * 32 + srow) * K + scol;

  f32x4 acc[4][4] = {};

  for (int k0 = 0; k0 < K; k0 += 64) {
    __syncthreads();
#pragma unroll
    for (int i = 0; i < 4; ++i) {
      GLL(ag + (size_t)(i * 8) * lda + k0, &A_lds[w * 32 + i * 8][0]);
      GLL(bg + (size_t)(i * 8) * K + k0, &B_lds[w * 32 + i * 8][0]);
    }
    __syncthreads();
#pragma unroll
    for (int kk = 0; kk < 2; ++kk) {
      bf16x8 a[4], bb[4];
#pragma unroll
      for (int m = 0; m < 4; ++m)
        a[m] = *reinterpret_cast<const bf16x8*>(&A_lds[wr * 64 + m * 16 + l15][kk * 32 + g * 8]);
#pragma unroll
      for (int n = 0; n < 4; ++n)
        bb[n] = *reinterpret_cast<const bf16x8*>(&B_lds[wc * 64 + n * 16 + l15][kk * 32 + g * 8]);
#pragma unroll
      for (int m = 0; m < 4; ++m)
#pragma unroll
        for (int n = 0; n < 4; ++n)
          acc[m][n] = __builtin_amdgcn_mfma_f32_16x16x32_bf16(a[m], bb[n], acc[m][n], 0, 0, 0);
    }
  }

#pragma unroll
  for (int m = 0; m < 4; ++m)
#pragma unroll
    for (int n = 0; n < 4; ++n)
#pragma unroll
      for (int r = 0; r < 4; ++r) {
        int row = m0 + wr * 64 + m * 16 + 4 * g + r;
        int col = n0 + wc * 64 + n * 16 + l15;
        C[(size_t)row * ldc + col] = (CT)acc[m][n][r];
      }
}

// ---------------- RoPE in-place; q additionally scaled by 0.125 (exact pow2) ----------------
__global__ __launch_bounds__(256) void rope_kernel(__bf16* __restrict__ qkv) {
  int idx = blockIdx.x * blockDim.x + threadIdx.x;
  int d = idx & 31;
  int h = (idx >> 5) & 15;
  int qk = (idx >> 9) & 1;
  int tok = idx >> 10;
  int t = tok & (SEQ - 1);
  size_t base = (size_t)tok * 3072 + (size_t)qk * 1024 + h * 64 + d;
  float x1 = (float)qkv[base];
  float x2 = (float)qkv[base + 32];
  float theta = exp2f(-(float)d * 0.41524101186092953f);
  float ang = (float)t * theta;
  float s, c;
  __sincosf(ang, &s, &c);
  float sc = (qk == 0) ? 0.125f : 1.0f;
  qkv[base] = (__bf16)((x1 * c - x2 * s) * sc);
  qkv[base + 32] = (__bf16)((x1 * s + x2 * c) * sc);
}

__device__ inline uint32_t pkbf(float a, float b) {
  union { __bf16 h[2]; uint32_t u; } z;
  z.h[0] = (__bf16)a; z.h[1] = (__bf16)b;
  return z.u;
}

// ---------------- causal flash attention, swapped-QK^T 32x32 in-register softmax ----------------
// 512 blocks (heavy-first), 4 waves. Block: 128 q-rows (wave w: qblk*128+w*32 .. +31).
// KVBLK=64. S^T = mfma(K,Q): lane owns q=lane&31 column; O^T = mfma(Vt,P): alpha/l per-lane.
__global__ __launch_bounds__(256) void attn_kernel(__bf16* __restrict__ qkv) {
  __shared__ __bf16 K_lds[64][72];   // [k][d]
  __shared__ __bf16 Vt_lds[64][72];  // [d][k], col ^ (8*((d>>3)&7))

  int tid = threadIdx.x;
  int w = tid >> 6, lane = tid & 63;
  int l31 = lane & 31, hi = lane >> 5;
  int bid = blockIdx.x;
  int bh = bid & 31;
  int qblk = 15 - (bid >> 5);        // heavy blocks first
  int b = bh >> 4, h = bh & 15;

  __bf16* qbase = qkv + (size_t)b * SEQ * 3072 + h * 64;
  const __bf16* kbase = qbase + 1024;
  const __bf16* vbase = qbase + 2048;

  int NT = 2 * (qblk + 1);
  int qw0 = qblk * 128 + w * 32;
  int nt_w = ((qw0 + 31) >> 6) + 1;  // this wave's active tiles
  int q_g = qw0 + l31;               // this lane's q row

  // staging coords
  int c8 = (tid & 7) * 8;
  int srow = tid >> 3;
  int vswz = c8;  // 8*((d>>3)&7) with d = c8

  // Q fragments (held whole loop): qf[ds] = Q[q_g][ds*16 + 8*hi .. +8]
  bf16x8 qf[4];
#pragma unroll
  for (int ds = 0; ds < 4; ++ds)
    qf[ds] = *reinterpret_cast<const bf16x8*>(qbase + (size_t)q_g * 3072 + ds * 16 + 8 * hi);

  f32x16 oacc[2] = {};  // O^T: [dt][reg] -> d = dt*32 + (r&3)+8*(r>>2)+4*hi, col q
  float m_run = -1e30f, l_run = 0.f;

  // stage tile 0
#pragma unroll
  for (int p = 0; p < 2; ++p) {
    int s = p * 32 + srow;
    *reinterpret_cast<uint4*>(&K_lds[s][c8]) =
        *reinterpret_cast<const uint4*>(kbase + (size_t)s * 3072 + c8);
    uint4 vv = *reinterpret_cast<const uint4*>(vbase + (size_t)s * 3072 + c8);
    const __bf16* vp = reinterpret_cast<const __bf16*>(&vv);
#pragma unroll
    for (int jj = 0; jj < 8; ++jj) Vt_lds[c8 + jj][s ^ vswz] = vp[jj];
  }
  __syncthreads();

  for (int jb = 0; jb < NT; ++jb) {
    bool pre = (jb + 1 < NT);
    uint4 kpre[2], vpre[2];
    if (pre) {
#pragma unroll
      for (int p = 0; p < 2; ++p) {
        int s = (jb + 1) * 64 + p * 32 + srow;
        kpre[p] = *reinterpret_cast<const uint4*>(kbase + (size_t)s * 3072 + c8);
        vpre[p] = *reinterpret_cast<const uint4*>(vbase + (size_t)s * 3072 + c8);
      }
    }

    if (jb < nt_w) {  // wave-active
      // ---- S^T = K · Q^T : sacc[kt], k_local = kt*32 + (r&3)+8*(r>>2)+4*hi, col q ----
      f32x16 sacc[2] = {};
      __builtin_amdgcn_s_setprio(1);
#pragma unroll
      for (int kt = 0; kt < 2; ++kt) {
#pragma unroll
        for (int ds = 0; ds < 4; ++ds) {
          bf16x8 kf = *reinterpret_cast<const bf16x8*>(&K_lds[kt * 32 + l31][ds * 16 + 8 * hi]);
          sacc[kt] = __builtin_amdgcn_mfma_f32_32x32x16_bf16(kf, qf[ds], sacc[kt], 0, 0, 0);
        }
      }
      __builtin_amdgcn_s_setprio(0);

      // ---- causal mask (only this wave's last tile crosses the diagonal) ----
      if (jb == nt_w - 1) {
#pragma unroll
        for (int kt = 0; kt < 2; ++kt)
#pragma unroll
          for (int r = 0; r < 16; ++r) {
            int k_g = jb * 64 + kt * 32 + (r & 3) + 8 * (r >> 2) + 4 * hi;
            if (k_g > q_g) sacc[kt][r] = -1e30f;
          }
      }

      // ---- row max (own 32 regs + partner via one swap) ----
      float tm = sacc[0][0];
#pragma unroll
      for (int r = 1; r < 16; ++r) tm = fmaxf(tm, sacc[0][r]);
#pragma unroll
      for (int r = 0; r < 16; ++r) tm = fmaxf(tm, sacc[1][r]);
      tm = fmaxf(tm, __shfl_xor(tm, 32));

      float m_new = fmaxf(m_run, tm);
      float alpha = __expf(m_run - m_new);
      m_run = m_new;

      // ---- exp in place + sum ----
      float sum = 0.f;
#pragma unroll
      for (int kt = 0; kt < 2; ++kt)
#pragma unroll
        for (int r = 0; r < 16; ++r) {
          float p = __expf(sacc[kt][r] - m_new);
          sacc[kt][r] = p;
          sum += p;
        }
      sum += __shfl_xor(sum, 32);
      l_run = l_run * alpha + sum;

      // ---- O rescale ----
#pragma unroll
      for (int dt = 0; dt < 2; ++dt)
#pragma unroll
        for (int r = 0; r < 16; ++r) oacc[dt][r] *= alpha;

      // ---- build P A/B-frag: pa[ks] = P[q][ks*16 + 8*hi + j], j=0..7 ----
      uint4 pa[4];
#pragma unroll
      for (int ks = 0; ks < 4; ++ks) {
        // pack from k-div8 = 2ks (A) and 2ks+1 (B); both static indices
        constexpr int KS[4] = {0, 1, 2, 3};
        int v0 = 2 * KS[ks], v1 = v0 + 1;
        int t0 = v0 >> 2, rb0 = 4 * (v0 & 3);
        int t1 = v1 >> 2, rb1 = 4 * (v1 & 3);
        uint32_t a01, a23, b01, b23;
        if (t0 == 0) { a01 = pkbf(sacc[0][rb0 + 0], sacc[0][rb0 + 1]);
                       a23 = pkbf(sacc[0][rb0 + 2], sacc[0][rb0 + 3]); }
        else         { a01 = pkbf(sacc[1][rb0 + 0], sacc[1][rb0 + 1]);
                       a23 = pkbf(sacc[1][rb0 + 2], sacc[1][rb0 + 3]); }
        if (t1 == 0) { b01 = pkbf(sacc[0][rb1 + 0], sacc[0][rb1 + 1]);
                       b23 = pkbf(sacc[0][rb1 + 2], sacc[0][rb1 + 3]); }
        else         { b01 = pkbf(sacc[1][rb1 + 0], sacc[1][rb1 + 1]);
                       b23 = pkbf(sacc[1][rb1 + 2], sacc[1][rb1 + 3]); }
        // transmit the pack the partner needs (kdiv8 = 2ks + partner_hi)
        uint32_t t01 = hi ? a01 : b01;
        uint32_t t23 = hi ? a23 : b23;
        uint32_t r01 = __shfl_xor(t01, 32);
        uint32_t r23 = __shfl_xor(t23, 32);
        uint32_t k01 = hi ? b01 : a01;  // keep: kdiv8 = 2ks + hi
        uint32_t k23 = hi ? b23 : a23;
        // j0..3 half comes from the hi=0 lane's values; j4..7 from hi=1 lane's
        pa[ks].x = hi ? r01 : k01;
        pa[ks].y = hi ? r23 : k23;
        pa[ks].z = hi ? k01 : r01;
        pa[ks].w = hi ? k23 : r23;
      }

      // ---- O^T += V^T · P^T ----
      __builtin_amdgcn_s_setprio(1);
#pragma unroll
      for (int dt = 0; dt < 2; ++dt) {
#pragma unroll
        for (int ks = 0; ks < 4; ++ks) {
          int d = dt * 32 + l31;
          int col = (ks * 16 + 8 * hi) ^ (8 * ((d >> 3) & 7));
          bf16x8 vf = *reinterpret_cast<const bf16x8*>(&Vt_lds[d][col]);
          oacc[dt] = __builtin_amdgcn_mfma_f32_32x32x16_bf16(
              vf, *reinterpret_cast<const bf16x8*>(&pa[ks]), oacc[dt], 0, 0, 0);
        }
      }
      __builtin_amdgcn_s_setprio(0);
    }

    if (pre) {
      __syncthreads();
#pragma unroll
      for (int p = 0; p < 2; ++p) {
        int s = p * 32 + srow;
        *reinterpret_cast<uint4*>(&K_lds[s][c8]) = kpre[p];
        const __bf16* vp = reinterpret_cast<const __bf16*>(&vpre[p]);
#pragma unroll
        for (int jj = 0; jj < 8; ++jj) Vt_lds[c8 + jj][s ^ vswz] = vp[jj];
      }
      __syncthreads();
    }
  }

  // ---- epilogue: y[q][d] = O^T[d][q] / l, into q-slot (block-exclusive rows) ----
  float inv = 1.0f / l_run;
#pragma unroll
  for (int dt = 0; dt < 2; ++dt)
#pragma unroll
    for (int u = 0; u < 4; ++u) {
      int d0 = dt * 32 + 8 * u + 4 * hi;
      alignas(8) __bf16 tmp[4];
#pragma unroll
      for (int m = 0; m < 4; ++m) tmp[m] = (__bf16)(oacc[dt][4 * u + m] * inv);
      *reinterpret_cast<uint2*>(qbase + (size_t)q_g * 3072 + d0) =
          *reinterpret_cast<const uint2*>(tmp);
    }
}

extern "C" void kernel_launch(void* const* d_in, const int* in_sizes, int n_in,
                              void* d_out, int out_size, void* d_ws, size_t ws_size,
                              hipStream_t stream) {
  const float* x = (const float*)d_in[0];
  const float* Wqkv = (const float*)d_in[1];
  const float* Wo = (const float*)d_in[2];
  float* out = (float*)d_out;

  __bf16* ws = (__bf16*)d_ws;
  __bf16* WqkvT = ws;                           // [3072][1024]
  __bf16* WoT = WqkvT + 3072 * 1024;            // [1024][1024]
  __bf16* qkv = WoT + 1024 * 1024;              // [4096][3072]
  __bf16* xbf = qkv + (size_t)4096 * 3072;      // [4096][1024]

  transpose_cvt<<<dim3(48, 16), 256, 0, stream>>>(Wqkv, WqkvT, 1024, 3072);
  transpose_cvt<<<dim3(16, 16), 256, 0, stream>>>(Wo, WoT, 1024, 1024);
  cvt_fp32_bf16<<<2048, 256, 0, stream>>>(x, xbf);

  gemm_bt_lds<__bf16><<<dim3(32, 24), 256, 0, stream>>>(xbf, WqkvT, qkv,
                                                        4096, 3072, 1024, 1024, 3072);
  rope_kernel<<<16384, 256, 0, stream>>>(qkv);

  attn_kernel<<<512, 256, 0, stream>>>(qkv);

  gemm_bt_lds<float><<<dim3(32, 8), 256, 0, stream>>>(qkv, WoT, out,
                                                      4096, 1024, 1024, 3072, 1024);
}

// Round 6
// 163.850 us; speedup vs baseline: 1.0595x; 1.0370x over previous
//
#include <hip/hip_runtime.h>

typedef __bf16 bf16x8 __attribute__((ext_vector_type(8)));
typedef float f32x4 __attribute__((ext_vector_type(4)));
typedef float f32x16 __attribute__((ext_vector_type(16)));

constexpr int SEQ = 2048;
constexpr int DMODEL = 1024;

#define GLL(gp, lp)                                                              \
  __builtin_amdgcn_global_load_lds((const __attribute__((address_space(1))) void*)(gp), \
                                   (__attribute__((address_space(3))) void*)(lp), 16, 0, 0)

// ---------------- transpose + fp32->bf16 convert: dst[C][R] = (bf16)src[R][C] ----------------
__global__ __launch_bounds__(256) void transpose_cvt(const float* __restrict__ src,
                                                     __bf16* __restrict__ dst,
                                                     int R, int C) {
  __shared__ __bf16 tile[64][72];
  int c0 = blockIdx.x * 64, r0 = blockIdx.y * 64;
  int t = threadIdx.x;
#pragma unroll
  for (int p = 0; p < 2; ++p) {
    int flat = p * 256 + t;
    int i = flat >> 3;
    int j8 = (flat & 7) * 8;
    const float* sp = &src[(size_t)(r0 + i) * C + c0 + j8];
    float4 f0 = *reinterpret_cast<const float4*>(sp);
    float4 f1 = *reinterpret_cast<const float4*>(sp + 4);
    tile[i][j8 + 0] = (__bf16)f0.x; tile[i][j8 + 1] = (__bf16)f0.y;
    tile[i][j8 + 2] = (__bf16)f0.z; tile[i][j8 + 3] = (__bf16)f0.w;
    tile[i][j8 + 4] = (__bf16)f1.x; tile[i][j8 + 5] = (__bf16)f1.y;
    tile[i][j8 + 6] = (__bf16)f1.z; tile[i][j8 + 7] = (__bf16)f1.w;
  }
  __syncthreads();
#pragma unroll
  for (int p = 0; p < 2; ++p) {
    int flat = p * 256 + t;
    int i = flat >> 3;
    int j8 = (flat & 7) * 8;
    alignas(16) __bf16 tmp[8];
#pragma unroll
    for (int jj = 0; jj < 8; ++jj) tmp[jj] = tile[j8 + jj][i];
    *reinterpret_cast<uint4*>(&dst[(size_t)(c0 + i) * R + r0 + j8]) =
        *reinterpret_cast<const uint4*>(tmp);
  }
}

// ---------------- fp32 -> bf16 bulk convert ----------------
__global__ __launch_bounds__(256) void cvt_fp32_bf16(const float* __restrict__ src,
                                                     __bf16* __restrict__ dst) {
  int i = blockIdx.x * 256 + threadIdx.x;
  const float* sp = src + (size_t)i * 8;
  float4 f0 = *reinterpret_cast<const float4*>(sp);
  float4 f1 = *reinterpret_cast<const float4*>(sp + 4);
  alignas(16) __bf16 tmp[8];
  tmp[0] = (__bf16)f0.x; tmp[1] = (__bf16)f0.y; tmp[2] = (__bf16)f0.z; tmp[3] = (__bf16)f0.w;
  tmp[4] = (__bf16)f1.x; tmp[5] = (__bf16)f1.y; tmp[6] = (__bf16)f1.z; tmp[7] = (__bf16)f1.w;
  *reinterpret_cast<uint4*>(dst + (size_t)i * 8) = *reinterpret_cast<const uint4*>(tmp);
}

// ---------------- V transpose: vt[bh][d][s] = qkv.v[b][s][h*64+d] ----------------
__global__ __launch_bounds__(256) void transpose_v(const __bf16* __restrict__ qkv,
                                                   __bf16* __restrict__ vt) {
  __shared__ __bf16 tile[64][72];
  int s0 = blockIdx.x * 64;
  int bh = blockIdx.y;
  int b = bh >> 4, h = bh & 15;
  const __bf16* src = qkv + (size_t)b * SEQ * 3072 + 2048 + h * 64;
  __bf16* dst = vt + (size_t)bh * 64 * SEQ;
  int t = threadIdx.x;
  {
    int i = t >> 2;            // 0..63 token
    int j8 = (t & 3) * 16;     // not used; need 64x64: 256 thr -> i=t>>2? 64*64/8=512 vec8
  }
#pragma unroll
  for (int p = 0; p < 2; ++p) {
    int flat = p * 256 + t;
    int i = flat >> 3;
    int j8 = (flat & 7) * 8;
    *reinterpret_cast<uint4*>(&tile[i][j8]) =
        *reinterpret_cast<const uint4*>(src + (size_t)(s0 + i) * 3072 + j8);
  }
  __syncthreads();
#pragma unroll
  for (int p = 0; p < 2; ++p) {
    int flat = p * 256 + t;
    int i = flat >> 3;          // d
    int j8 = (flat & 7) * 8;    // s offset
    alignas(16) __bf16 tmp[8];
#pragma unroll
    for (int jj = 0; jj < 8; ++jj) tmp[jj] = tile[j8 + jj][i];
    *reinterpret_cast<uint4*>(dst + (size_t)i * SEQ + s0 + j8) =
        *reinterpret_cast<const uint4*>(tmp);
  }
}

// ---------------- GEMM (m97 structure): C[M][N] = A[M][K] * BT[N][K]^T ----------------
template <typename CT, int BN>
__global__ __launch_bounds__(256) void gemm_bt_lds(const __bf16* __restrict__ A,
                                                   const __bf16* __restrict__ BT,
                                                   CT* __restrict__ C,
                                                   int M, int N, int K, int lda, int ldc) {
  constexpr int MF = (BN == 128) ? 4 : 2;
  __shared__ __align__(16) __bf16 A_lds[128][64];
  __shared__ __align__(16) __bf16 B_lds[BN][64];
  int tid = threadIdx.x;
  int lane = tid & 63, w = tid >> 6;
  int g = lane >> 4, l15 = lane & 15;
  int wr = (BN == 128) ? (w >> 1) : w;
  int wc = (BN == 128) ? (w & 1) : 0;
  int m0 = blockIdx.x * 128, n0 = blockIdx.y * BN;
  int srow = lane >> 3, scol = (lane & 7) * 8;

  const __bf16* ag = A + (size_t)(m0 + w * 32 + srow) * lda + scol;
  const __bf16* bg = BT + (size_t)(n0 + w * (BN / 4) + srow) * K + scol;

  f32x4 acc[MF][4] = {};

  for (int k0 = 0; k0 < K; k0 += 64) {
    __syncthreads();
#pragma unroll
    for (int i = 0; i < 4; ++i)
      GLL(ag + (size_t)(i * 8) * lda + k0, &A_lds[w * 32 + i * 8][0]);
#pragma unroll
    for (int i = 0; i < BN / 32; ++i)
      GLL(bg + (size_t)(i * 8) * K + k0, &B_lds[w * (BN / 4) + i * 8][0]);
    __syncthreads();
#pragma unroll
    for (int kk = 0; kk < 2; ++kk) {
      bf16x8 a[MF], bb[4];
#pragma unroll
      for (int m = 0; m < MF; ++m)
        a[m] = *reinterpret_cast<const bf16x8*>(&A_lds[wr * (MF * 16) + m * 16 + l15][kk * 32 + g * 8]);
#pragma unroll
      for (int n = 0; n < 4; ++n)
        bb[n] = *reinterpret_cast<const bf16x8*>(&B_lds[wc * 64 + n * 16 + l15][kk * 32 + g * 8]);
#pragma unroll
      for (int m = 0; m < MF; ++m)
#pragma unroll
        for (int n = 0; n < 4; ++n)
          acc[m][n] = __builtin_amdgcn_mfma_f32_16x16x32_bf16(a[m], bb[n], acc[m][n], 0, 0, 0);
    }
  }

#pragma unroll
  for (int m = 0; m < MF; ++m)
#pragma unroll
    for (int n = 0; n < 4; ++n)
#pragma unroll
      for (int r = 0; r < 4; ++r) {
        int row = m0 + wr * (MF * 16) + m * 16 + 4 * g + r;
        int col = n0 + wc * 64 + n * 16 + l15;
        C[(size_t)row * ldc + col] = (CT)acc[m][n][r];
      }
}

// ---------------- RoPE in-place (vectorized pairs); q scaled by 0.125*log2e ----------------
__global__ __launch_bounds__(256) void rope_kernel(__bf16* __restrict__ qkv) {
  int idx = blockIdx.x * 256 + threadIdx.x;  // 2M threads
  int d2 = idx & 15;           // pair: d = 2*d2, 2*d2+1
  int h = (idx >> 4) & 15;
  int qk = (idx >> 8) & 1;
  int tok = idx >> 9;
  int t = tok & (SEQ - 1);
  size_t base = (size_t)tok * 3072 + (size_t)qk * 1024 + h * 64 + d2 * 2;
  union { uint32_t u; __bf16 h2[2]; } a1, a2, o1, o2;
  a1.u = *reinterpret_cast<const uint32_t*>(&qkv[base]);
  a2.u = *reinterpret_cast<const uint32_t*>(&qkv[base + 32]);
  float sc = (qk == 0) ? 0.18033688011112042f : 1.0f;  // 0.125 * log2(e) folded into q
  float tf = (float)t;
#pragma unroll
  for (int j = 0; j < 2; ++j) {
    int d = 2 * d2 + j;
    float x1 = (float)a1.h2[j];
    float x2 = (float)a2.h2[j];
    float theta = exp2f(-(float)d * 0.41524101186092953f);
    float s, c;
    __sincosf(tf * theta, &s, &c);
    o1.h2[j] = (__bf16)((x1 * c - x2 * s) * sc);
    o2.h2[j] = (__bf16)((x1 * s + x2 * c) * sc);
  }
  *reinterpret_cast<uint32_t*>(&qkv[base]) = o1.u;
  *reinterpret_cast<uint32_t*>(&qkv[base + 32]) = o2.u;
}

__device__ inline uint32_t pkbf(float a, float b) {
  union { __bf16 h[2]; uint32_t u; } z;
  z.h[0] = (__bf16)a; z.h[1] = (__bf16)b;
  return z.u;
}

// ---------------- causal flash attention ----------------
// 1024 blocks (heavy-first), 2 waves x 32 q-rows. KVBLK=64, double-buffered GLL staging,
// XOR-swizzled K/Vt via pre-swizzled global source. Softmax in exp2 domain (q pre-scaled).
__global__ __launch_bounds__(128, 2) void attn_kernel(__bf16* __restrict__ qkv,
                                                      const __bf16* __restrict__ vt) {
  __shared__ __align__(16) __bf16 K_lds[2][64][64];
  __shared__ __align__(16) __bf16 Vt_lds[2][64][64];

  int tid = threadIdx.x;
  int w = tid >> 6, lane = tid & 63;
  int l31 = lane & 31, hi = lane >> 5;
  int bid = blockIdx.x;
  int bh = bid & 31;
  int qc = 31 - (bid >> 5);          // heavy blocks first
  int b = bh >> 4, h = bh & 15;

  __bf16* qbase = qkv + (size_t)b * SEQ * 3072 + h * 64;
  const __bf16* kbase = qbase + 1024;
  const __bf16* vtb = vt + (size_t)bh * 64 * SEQ;

  int NT = qc + 1;
  int q_g = qc * 64 + w * 32 + l31;  // this lane's q row

  // staging: lane covers phys (row = G*8 + lane/8, elem = 8*(lane&7));
  // source elem = 8*((lane&7) ^ (lane/8))  [inverse swizzle]
  int r8 = lane >> 3;
  int cxe = 8 * ((lane & 7) ^ r8);

  auto STAGE = [&](int bufv, int t) {
#pragma unroll
    for (int g = 0; g < 2; ++g) {
      int R = (w * 2 + g) * 16;  // 4 GLL pairs per wave? rows per GLL = 8
      // two GLLs per g: rows R..R+7 and R+8..R+15
      GLL(kbase + (size_t)(t * 64 + R + r8) * 3072 + cxe, &K_lds[bufv][R][0]);
      GLL(kbase + (size_t)(t * 64 + R + 8 + r8) * 3072 + cxe, &K_lds[bufv][R + 8][0]);
      GLL(vtb + (size_t)(R + r8) * SEQ + t * 64 + cxe, &Vt_lds[bufv][R][0]);
      GLL(vtb + (size_t)(R + 8 + r8) * SEQ + t * 64 + cxe, &Vt_lds[bufv][R + 8][0]);
    }
  };

  // Q fragments (exp2-domain pre-scaled by rope)
  bf16x8 qf[4];
#pragma unroll
  for (int ds = 0; ds < 4; ++ds)
    qf[ds] = *reinterpret_cast<const bf16x8*>(qbase + (size_t)q_g * 3072 + ds * 16 + 8 * hi);

  f32x16 oacc[2] = {};
  float m_run = -1e30f, l_run = 0.f;

  STAGE(0, 0);
  __syncthreads();

  int buf = 0;
  for (int jb = 0; jb < NT; ++jb) {
    bool pre = (jb + 1 < NT);
    if (pre) STAGE(buf ^ 1, jb + 1);

    // ---- S^T = K · Q^T ----
    f32x16 sacc[2] = {};
    __builtin_amdgcn_s_setprio(1);
#pragma unroll
    for (int kt = 0; kt < 2; ++kt) {
#pragma unroll
      for (int ds = 0; ds < 4; ++ds) {
        bf16x8 kf = *reinterpret_cast<const bf16x8*>(
            &K_lds[buf][kt * 32 + l31][(ds * 16 + 8 * hi) ^ ((l31 & 7) * 8)]);
        sacc[kt] = __builtin_amdgcn_mfma_f32_32x32x16_bf16(kf, qf[ds], sacc[kt], 0, 0, 0);
      }
    }
    __builtin_amdgcn_s_setprio(0);

    // ---- causal mask on last tile ----
    if (jb == NT - 1) {
#pragma unroll
      for (int kt = 0; kt < 2; ++kt)
#pragma unroll
        for (int r = 0; r < 16; ++r) {
          int k_g = jb * 64 + kt * 32 + (r & 3) + 8 * (r >> 2) + 4 * hi;
          if (k_g > q_g) sacc[kt][r] = -1e30f;
        }
    }

    // ---- row max: elementwise + tree (depth 5) + partner swap ----
    float mx[8];
#pragma unroll
    for (int r = 0; r < 8; ++r)
      mx[r] = fmaxf(fmaxf(sacc[0][r], sacc[0][r + 8]), fmaxf(sacc[1][r], sacc[1][r + 8]));
    float m01 = fmaxf(fmaxf(mx[0], mx[1]), fmaxf(mx[2], mx[3]));
    float m23 = fmaxf(fmaxf(mx[4], mx[5]), fmaxf(mx[6], mx[7]));
    float tm = fmaxf(m01, m23);
    tm = fmaxf(tm, __shfl_xor(tm, 32));

    // ---- T13 defer-max ----
    float m_new, alpha;
    if (__all(tm - m_run <= 8.f)) {
      m_new = m_run;
      alpha = 1.f;
    } else {
      m_new = fmaxf(m_run, tm);
      alpha = exp2f(m_run - m_new);
      m_run = m_new;
#pragma unroll
      for (int dt = 0; dt < 2; ++dt)
#pragma unroll
        for (int r = 0; r < 16; ++r) oacc[dt][r] *= alpha;
    }

    // ---- p = exp2(s - m); sum via 4 parallel chains ----
    float s0 = 0.f, s1 = 0.f, s2 = 0.f, s3 = 0.f;
#pragma unroll
    for (int kt = 0; kt < 2; ++kt) {
#pragma unroll
      for (int r = 0; r < 16; r += 4) {
        float p0 = exp2f(sacc[kt][r + 0] - m_new);
        float p1 = exp2f(sacc[kt][r + 1] - m_new);
        float p2 = exp2f(sacc[kt][r + 2] - m_new);
        float p3 = exp2f(sacc[kt][r + 3] - m_new);
        sacc[kt][r + 0] = p0; sacc[kt][r + 1] = p1;
        sacc[kt][r + 2] = p2; sacc[kt][r + 3] = p3;
        s0 += p0; s1 += p1; s2 += p2; s3 += p3;
      }
    }
    float sum = (s0 + s1) + (s2 + s3);
    sum += __shfl_xor(sum, 32);
    l_run = l_run * alpha + sum;

    // ---- build P fragments (lane q-row -> A/B frag via packs + one swap per pair) ----
    uint4 pa[4];
#pragma unroll
    for (int ks = 0; ks < 4; ++ks) {
      int v0 = 2 * ks, v1 = v0 + 1;
      int t0 = v0 >> 2, rb0 = 4 * (v0 & 3);
      int t1 = v1 >> 2, rb1 = 4 * (v1 & 3);
      uint32_t a01, a23, b01, b23;
      if (t0 == 0) { a01 = pkbf(sacc[0][rb0 + 0], sacc[0][rb0 + 1]);
                     a23 = pkbf(sacc[0][rb0 + 2], sacc[0][rb0 + 3]); }
      else         { a01 = pkbf(sacc[1][rb0 + 0], sacc[1][rb0 + 1]);
                     a23 = pkbf(sacc[1][rb0 + 2], sacc[1][rb0 + 3]); }
      if (t1 == 0) { b01 = pkbf(sacc[0][rb1 + 0], sacc[0][rb1 + 1]);
                     b23 = pkbf(sacc[0][rb1 + 2], sacc[0][rb1 + 3]); }
      else         { b01 = pkbf(sacc[1][rb1 + 0], sacc[1][rb1 + 1]);
                     b23 = pkbf(sacc[1][rb1 + 2], sacc[1][rb1 + 3]); }
      uint32_t t01 = hi ? a01 : b01;
      uint32_t t23 = hi ? a23 : b23;
      uint32_t r01 = __shfl_xor(t01, 32);
      uint32_t r23 = __shfl_xor(t23, 32);
      uint32_t k01 = hi ? b01 : a01;
      uint32_t k23 = hi ? b23 : a23;
      pa[ks].x = hi ? r01 : k01;
      pa[ks].y = hi ? r23 : k23;
      pa[ks].z = hi ? k01 : r01;
      pa[ks].w = hi ? k23 : r23;
    }

    // ---- O^T += V^T · P^T ----
    __builtin_amdgcn_s_setprio(1);
#pragma unroll
    for (int dt = 0; dt < 2; ++dt) {
#pragma unroll
      for (int ks = 0; ks < 4; ++ks) {
        bf16x8 vf = *reinterpret_cast<const bf16x8*>(
            &Vt_lds[buf][dt * 32 + l31][(ks * 16 + 8 * hi) ^ ((l31 & 7) * 8)]);
        oacc[dt] = __builtin_amdgcn_mfma_f32_32x32x16_bf16(
            vf, *reinterpret_cast<const bf16x8*>(&pa[ks]), oacc[dt], 0, 0, 0);
      }
    }
    __builtin_amdgcn_s_setprio(0);

    if (pre) {
      asm volatile("s_waitcnt vmcnt(0)" ::: "memory");
      __syncthreads();
    }
    buf ^= 1;
  }

  // ---- epilogue: y[q][d] = O^T[d][q] / l into q-slot ----
  float inv = 1.0f / l_run;
#pragma unroll
  for (int dt = 0; dt < 2; ++dt)
#pragma unroll
    for (int u = 0; u < 4; ++u) {
      int d0 = dt * 32 + 8 * u + 4 * hi;
      alignas(8) __bf16 tmp[4];
#pragma unroll
      for (int m = 0; m < 4; ++m) tmp[m] = (__bf16)(oacc[dt][4 * u + m] * inv);
      *reinterpret_cast<uint2*>(qbase + (size_t)q_g * 3072 + d0) =
          *reinterpret_cast<const uint2*>(tmp);
    }
}

extern "C" void kernel_launch(void* const* d_in, const int* in_sizes, int n_in,
                              void* d_out, int out_size, void* d_ws, size_t ws_size,
                              hipStream_t stream) {
  const float* x = (const float*)d_in[0];
  const float* Wqkv = (const float*)d_in[1];
  const float* Wo = (const float*)d_in[2];
  float* out = (float*)d_out;

  __bf16* ws = (__bf16*)d_ws;
  __bf16* WqkvT = ws;                           // [3072][1024]  6 MB
  __bf16* WoT = WqkvT + 3072 * 1024;            // [1024][1024]  2 MB
  __bf16* qkv = WoT + 1024 * 1024;              // [4096][3072] 24 MB
  __bf16* xbf = qkv + (size_t)4096 * 3072;      // [4096][1024]  8 MB (reused as vt)
  __bf16* vtb = xbf;                            // vt[32][64][2048] after gemm1

  transpose_cvt<<<dim3(48, 16), 256, 0, stream>>>(Wqkv, WqkvT, 1024, 3072);
  transpose_cvt<<<dim3(16, 16), 256, 0, stream>>>(Wo, WoT, 1024, 1024);
  cvt_fp32_bf16<<<2048, 256, 0, stream>>>(x, xbf);

  gemm_bt_lds<__bf16, 128><<<dim3(32, 24), 256, 0, stream>>>(xbf, WqkvT, qkv,
                                                             4096, 3072, 1024, 1024, 3072);
  rope_kernel<<<8192, 256, 0, stream>>>(qkv);
  transpose_v<<<dim3(32, 32), 256, 0, stream>>>(qkv, vtb);

  attn_kernel<<<1024, 128, 0, stream>>>(qkv, vtb);

  gemm_bt_lds<float, 64><<<dim3(32, 16), 256, 0, stream>>>(qkv, WoT, out,
                                                           4096, 1024, 1024, 3072, 1024);
}

// Round 7
// 159.632 us; speedup vs baseline: 1.0874x; 1.0264x over previous
//
#include <hip/hip_runtime.h>

typedef __bf16 bf16x8 __attribute__((ext_vector_type(8)));
typedef float f32x4 __attribute__((ext_vector_type(4)));
typedef float f32x16 __attribute__((ext_vector_type(16)));

constexpr int SEQ = 2048;
constexpr int DMODEL = 1024;

#define GLL(gp, lp)                                                              \
  __builtin_amdgcn_global_load_lds((const __attribute__((address_space(1))) void*)(gp), \
                                   (__attribute__((address_space(3))) void*)(lp), 16, 0, 0)

// ---------------- transpose + fp32->bf16 convert: dst[C][R] = (bf16)src[R][C] ----------------
__global__ __launch_bounds__(256) void transpose_cvt(const float* __restrict__ src,
                                                     __bf16* __restrict__ dst,
                                                     int R, int C) {
  __shared__ __bf16 tile[64][72];
  int c0 = blockIdx.x * 64, r0 = blockIdx.y * 64;
  int t = threadIdx.x;
#pragma unroll
  for (int p = 0; p < 2; ++p) {
    int flat = p * 256 + t;
    int i = flat >> 3;
    int j8 = (flat & 7) * 8;
    const float* sp = &src[(size_t)(r0 + i) * C + c0 + j8];
    float4 f0 = *reinterpret_cast<const float4*>(sp);
    float4 f1 = *reinterpret_cast<const float4*>(sp + 4);
    tile[i][j8 + 0] = (__bf16)f0.x; tile[i][j8 + 1] = (__bf16)f0.y;
    tile[i][j8 + 2] = (__bf16)f0.z; tile[i][j8 + 3] = (__bf16)f0.w;
    tile[i][j8 + 4] = (__bf16)f1.x; tile[i][j8 + 5] = (__bf16)f1.y;
    tile[i][j8 + 6] = (__bf16)f1.z; tile[i][j8 + 7] = (__bf16)f1.w;
  }
  __syncthreads();
#pragma unroll
  for (int p = 0; p < 2; ++p) {
    int flat = p * 256 + t;
    int i = flat >> 3;
    int j8 = (flat & 7) * 8;
    alignas(16) __bf16 tmp[8];
#pragma unroll
    for (int jj = 0; jj < 8; ++jj) tmp[jj] = tile[j8 + jj][i];
    *reinterpret_cast<uint4*>(&dst[(size_t)(c0 + i) * R + r0 + j8]) =
        *reinterpret_cast<const uint4*>(tmp);
  }
}

// ---------------- fp32 -> bf16 bulk convert ----------------
__global__ __launch_bounds__(256) void cvt_fp32_bf16(const float* __restrict__ src,
                                                     __bf16* __restrict__ dst) {
  int i = blockIdx.x * 256 + threadIdx.x;
  const float* sp = src + (size_t)i * 8;
  float4 f0 = *reinterpret_cast<const float4*>(sp);
  float4 f1 = *reinterpret_cast<const float4*>(sp + 4);
  alignas(16) __bf16 tmp[8];
  tmp[0] = (__bf16)f0.x; tmp[1] = (__bf16)f0.y; tmp[2] = (__bf16)f0.z; tmp[3] = (__bf16)f0.w;
  tmp[4] = (__bf16)f1.x; tmp[5] = (__bf16)f1.y; tmp[6] = (__bf16)f1.z; tmp[7] = (__bf16)f1.w;
  *reinterpret_cast<uint4*>(dst + (size_t)i * 8) = *reinterpret_cast<const uint4*>(tmp);
}

// ---------------- sincos table: sct[t][j] = (cos, sin)(t * 10000^(-j/32)) ----------------
__global__ __launch_bounds__(256) void build_sct(float2* __restrict__ sct) {
  int i = blockIdx.x * 256 + threadIdx.x;  // 65536
  int t = i >> 5, j = i & 31;
  float theta = exp2f(-(float)j * 0.41524101186092953f);
  float s, c;
  __sincosf((float)t * theta, &s, &c);
  sct[i] = make_float2(c, s);
}

// ---------------- V transpose: vt[bh][d][s] = qkv.v[b][s][h*64+d] ----------------
__global__ __launch_bounds__(256) void transpose_v(const __bf16* __restrict__ qkv,
                                                   __bf16* __restrict__ vt) {
  __shared__ __bf16 tile[64][72];
  int s0 = blockIdx.x * 64;
  int bh = blockIdx.y;
  int b = bh >> 4, h = bh & 15;
  const __bf16* src = qkv + (size_t)b * SEQ * 3072 + 2048 + h * 64;
  __bf16* dst = vt + (size_t)bh * 64 * SEQ;
  int t = threadIdx.x;
#pragma unroll
  for (int p = 0; p < 2; ++p) {
    int flat = p * 256 + t;
    int i = flat >> 3;
    int j8 = (flat & 7) * 8;
    *reinterpret_cast<uint4*>(&tile[i][j8]) =
        *reinterpret_cast<const uint4*>(src + (size_t)(s0 + i) * 3072 + j8);
  }
  __syncthreads();
#pragma unroll
  for (int p = 0; p < 2; ++p) {
    int flat = p * 256 + t;
    int i = flat >> 3;          // d
    int j8 = (flat & 7) * 8;    // s offset
    alignas(16) __bf16 tmp[8];
#pragma unroll
    for (int jj = 0; jj < 8; ++jj) tmp[jj] = tile[j8 + jj][i];
    *reinterpret_cast<uint4*>(dst + (size_t)i * SEQ + s0 + j8) =
        *reinterpret_cast<const uint4*>(tmp);
  }
}

// ---------------- GEMM (m97 structure): C[M][N] = A[M][K] * BT[N][K]^T ----------------
// ROPE: apply rotary embedding (+0.125*log2e scale on q) in the epilogue (gemm1 only).
template <typename CT, int BN, bool ROPE>
__global__ __launch_bounds__(256) void gemm_bt_lds(const __bf16* __restrict__ A,
                                                   const __bf16* __restrict__ BT,
                                                   CT* __restrict__ C,
                                                   int M, int N, int K, int lda, int ldc,
                                                   const float2* __restrict__ sct) {
  constexpr int MF = (BN == 128) ? 4 : 2;
  __shared__ __align__(16) __bf16 A_lds[128][64];
  __shared__ __align__(16) __bf16 B_lds[BN][64];
  int tid = threadIdx.x;
  int lane = tid & 63, w = tid >> 6;
  int g = lane >> 4, l15 = lane & 15;
  int wr = (BN == 128) ? (w >> 1) : w;
  int wc = (BN == 128) ? (w & 1) : 0;
  int m0 = blockIdx.x * 128, n0 = blockIdx.y * BN;
  int srow = lane >> 3, scol = (lane & 7) * 8;

  const __bf16* ag = A + (size_t)(m0 + w * 32 + srow) * lda + scol;
  const __bf16* bg = BT + (size_t)(n0 + w * (BN / 4) + srow) * K + scol;

  f32x4 acc[MF][4] = {};

  for (int k0 = 0; k0 < K; k0 += 64) {
    __syncthreads();
#pragma unroll
    for (int i = 0; i < 4; ++i)
      GLL(ag + (size_t)(i * 8) * lda + k0, &A_lds[w * 32 + i * 8][0]);
#pragma unroll
    for (int i = 0; i < BN / 32; ++i)
      GLL(bg + (size_t)(i * 8) * K + k0, &B_lds[w * (BN / 4) + i * 8][0]);
    __syncthreads();
#pragma unroll
    for (int kk = 0; kk < 2; ++kk) {
      bf16x8 a[MF], bb[4];
#pragma unroll
      for (int m = 0; m < MF; ++m)
        a[m] = *reinterpret_cast<const bf16x8*>(&A_lds[wr * (MF * 16) + m * 16 + l15][kk * 32 + g * 8]);
#pragma unroll
      for (int n = 0; n < 4; ++n)
        bb[n] = *reinterpret_cast<const bf16x8*>(&B_lds[wc * 64 + n * 16 + l15][kk * 32 + g * 8]);
#pragma unroll
      for (int m = 0; m < MF; ++m)
#pragma unroll
        for (int n = 0; n < 4; ++n)
          acc[m][n] = __builtin_amdgcn_mfma_f32_16x16x32_bf16(a[m], bb[n], acc[m][n], 0, 0, 0);
    }
  }

  if constexpr (ROPE) {
    // wave's 64-col span = exactly one head; d = n*16+l15; pairs (n, n+2) <-> (d, d+32)
    bool isq = (n0 < 1024), isk = (n0 >= 1024 && n0 < 2048);
    if (isq || isk) {
      float sc = isq ? 0.18033688011112042f : 1.0f;  // 0.125 * log2(e) for q (exp2 softmax)
#pragma unroll
      for (int m = 0; m < MF; ++m)
#pragma unroll
        for (int r = 0; r < 4; ++r) {
          int row = m0 + wr * (MF * 16) + m * 16 + 4 * g + r;
          int t = row & (SEQ - 1);
#pragma unroll
          for (int n = 0; n < 2; ++n) {
            int j = n * 16 + l15;  // d in 0..31
            float2 cs = sct[(t << 5) + j];
            float x1 = acc[m][n][r], x2 = acc[m][n + 2][r];
            acc[m][n][r]     = (x1 * cs.x - x2 * cs.y) * sc;
            acc[m][n + 2][r] = (x1 * cs.y + x2 * cs.x) * sc;
          }
        }
    }
  }

#pragma unroll
  for (int m = 0; m < MF; ++m)
#pragma unroll
    for (int n = 0; n < 4; ++n)
#pragma unroll
      for (int r = 0; r < 4; ++r) {
        int row = m0 + wr * (MF * 16) + m * 16 + 4 * g + r;
        int col = n0 + wc * 64 + n * 16 + l15;
        C[(size_t)row * ldc + col] = (CT)acc[m][n][r];
      }
}

__device__ inline uint32_t pkbf(float a, float b) {
  union { __bf16 h[2]; uint32_t u; } z;
  z.h[0] = (__bf16)a; z.h[1] = (__bf16)b;
  return z.u;
}

// ---------------- causal flash attention with split-K ----------------
// 1536 items: it<32 -> split halves of qc=31-(it>>1); it>=32 -> single qc=47-it.
// 2 waves x 32 q-rows. K in LDS (dbuf, swizzled, GLL); V^T read global->reg.
// Split items write unnormalized O^T (bf16) into the dead v-slot + (m,l) to pml.
__global__ __launch_bounds__(128, 3) void attn_kernel(__bf16* __restrict__ qkv,
                                                      const __bf16* __restrict__ vt,
                                                      float* __restrict__ pml) {
  __shared__ __align__(16) __bf16 K_lds[2][64][64];

  int tid = threadIdx.x;
  int w = tid >> 6, lane = tid & 63;
  int l31 = lane & 31, hi = lane >> 5;
  int bid = blockIdx.x;
  int it = bid >> 5, bh = bid & 31;
  int b = bh >> 4, h = bh & 15;

  int qc, kv0, kv1, half;
  bool split;
  if (it < 32) {
    qc = 31 - (it >> 1);
    half = it & 1;
    int NTf = qc + 1;
    int hs = (NTf + 1) >> 1;
    kv0 = half ? hs : 0;
    kv1 = half ? NTf : hs;
    split = true;
  } else {
    qc = 47 - it;
    kv0 = 0;
    kv1 = qc + 1;
    split = false;
    half = 0;
  }
  int NT = kv1 - kv0;

  __bf16* qbase = qkv + (size_t)b * SEQ * 3072 + h * 64;
  const __bf16* kbase = qbase + 1024;
  const __bf16* vtb = vt + (size_t)bh * 64 * SEQ;

  int q_g = qc * 64 + w * 32 + l31;  // lane's global q row (within b)

  // K staging coords (pre-swizzled source)
  int r8 = lane >> 3;
  int cxe = 8 * ((lane & 7) ^ r8);

  auto STAGE = [&](int bufv, int t) {
#pragma unroll
    for (int i = 0; i < 4; ++i) {
      int R = w * 32 + i * 8;
      GLL(kbase + (size_t)(t * 64 + R + r8) * 3072 + cxe, &K_lds[bufv][R][0]);
    }
  };

  // Q fragments
  bf16x8 qf[4];
#pragma unroll
  for (int ds = 0; ds < 4; ++ds)
    qf[ds] = *reinterpret_cast<const bf16x8*>(qbase + (size_t)q_g * 3072 + ds * 16 + 8 * hi);

  f32x16 oacc[2] = {};
  float m_run = -1e30f, l_run = 0.f;

  STAGE(0, kv0);
  __syncthreads();

  int buf = 0;
  for (int jb = 0; jb < NT; ++jb) {
    int kt_g = kv0 + jb;
    bool pre = (jb + 1 < NT);
    if (pre) STAGE(buf ^ 1, kt_g + 1);

    // ---- V^T prefetch (global->reg, consumed after softmax) ----
    uint4 vr[8];
#pragma unroll
    for (int dt = 0; dt < 2; ++dt)
#pragma unroll
      for (int ks = 0; ks < 4; ++ks)
        vr[dt * 4 + ks] = *reinterpret_cast<const uint4*>(
            vtb + (size_t)(dt * 32 + l31) * SEQ + kt_g * 64 + ks * 16 + 8 * hi);

    // ---- S^T = K · Q^T ----
    f32x16 sacc[2] = {};
    __builtin_amdgcn_s_setprio(1);
#pragma unroll
    for (int kt = 0; kt < 2; ++kt) {
#pragma unroll
      for (int ds = 0; ds < 4; ++ds) {
        bf16x8 kf = *reinterpret_cast<const bf16x8*>(
            &K_lds[buf][kt * 32 + l31][(ds * 16 + 8 * hi) ^ ((l31 & 7) * 8)]);
        sacc[kt] = __builtin_amdgcn_mfma_f32_32x32x16_bf16(kf, qf[ds], sacc[kt], 0, 0, 0);
      }
    }
    __builtin_amdgcn_s_setprio(0);

    // ---- causal mask on the diagonal tile ----
    if (kt_g == qc) {
#pragma unroll
      for (int kt = 0; kt < 2; ++kt)
#pragma unroll
        for (int r = 0; r < 16; ++r) {
          int k_g = kt_g * 64 + kt * 32 + (r & 3) + 8 * (r >> 2) + 4 * hi;
          if (k_g > q_g) sacc[kt][r] = -1e30f;
        }
    }

    // ---- row max: elementwise + tree + partner swap ----
    float mx[8];
#pragma unroll
    for (int r = 0; r < 8; ++r)
      mx[r] = fmaxf(fmaxf(sacc[0][r], sacc[0][r + 8]), fmaxf(sacc[1][r], sacc[1][r + 8]));
    float m01 = fmaxf(fmaxf(mx[0], mx[1]), fmaxf(mx[2], mx[3]));
    float m23 = fmaxf(fmaxf(mx[4], mx[5]), fmaxf(mx[6], mx[7]));
    float tm = fmaxf(m01, m23);
    tm = fmaxf(tm, __shfl_xor(tm, 32));

    // ---- T13 defer-max ----
    float m_new, alpha;
    if (__all(tm - m_run <= 8.f)) {
      m_new = m_run;
      alpha = 1.f;
    } else {
      m_new = fmaxf(m_run, tm);
      alpha = exp2f(m_run - m_new);
      m_run = m_new;
#pragma unroll
      for (int dt = 0; dt < 2; ++dt)
#pragma unroll
        for (int r = 0; r < 16; ++r) oacc[dt][r] *= alpha;
    }

    // ---- p = exp2(s - m); 4 parallel sum chains ----
    float s0 = 0.f, s1 = 0.f, s2 = 0.f, s3 = 0.f;
#pragma unroll
    for (int kt = 0; kt < 2; ++kt) {
#pragma unroll
      for (int r = 0; r < 16; r += 4) {
        float p0 = exp2f(sacc[kt][r + 0] - m_new);
        float p1 = exp2f(sacc[kt][r + 1] - m_new);
        float p2 = exp2f(sacc[kt][r + 2] - m_new);
        float p3 = exp2f(sacc[kt][r + 3] - m_new);
        sacc[kt][r + 0] = p0; sacc[kt][r + 1] = p1;
        sacc[kt][r + 2] = p2; sacc[kt][r + 3] = p3;
        s0 += p0; s1 += p1; s2 += p2; s3 += p3;
      }
    }
    float sum = (s0 + s1) + (s2 + s3);
    sum += __shfl_xor(sum, 32);
    l_run = l_run * alpha + sum;

    // ---- build P fragments ----
    uint4 pa[4];
#pragma unroll
    for (int ks = 0; ks < 4; ++ks) {
      int v0 = 2 * ks, v1 = v0 + 1;
      int t0 = v0 >> 2, rb0 = 4 * (v0 & 3);
      int t1 = v1 >> 2, rb1 = 4 * (v1 & 3);
      uint32_t a01, a23, b01, b23;
      if (t0 == 0) { a01 = pkbf(sacc[0][rb0 + 0], sacc[0][rb0 + 1]);
                     a23 = pkbf(sacc[0][rb0 + 2], sacc[0][rb0 + 3]); }
      else         { a01 = pkbf(sacc[1][rb0 + 0], sacc[1][rb0 + 1]);
                     a23 = pkbf(sacc[1][rb0 + 2], sacc[1][rb0 + 3]); }
      if (t1 == 0) { b01 = pkbf(sacc[0][rb1 + 0], sacc[0][rb1 + 1]);
                     b23 = pkbf(sacc[0][rb1 + 2], sacc[0][rb1 + 3]); }
      else         { b01 = pkbf(sacc[1][rb1 + 0], sacc[1][rb1 + 1]);
                     b23 = pkbf(sacc[1][rb1 + 2], sacc[1][rb1 + 3]); }
      uint32_t t01 = hi ? a01 : b01;
      uint32_t t23 = hi ? a23 : b23;
      uint32_t r01 = __shfl_xor(t01, 32);
      uint32_t r23 = __shfl_xor(t23, 32);
      uint32_t k01 = hi ? b01 : a01;
      uint32_t k23 = hi ? b23 : a23;
      pa[ks].x = hi ? r01 : k01;
      pa[ks].y = hi ? r23 : k23;
      pa[ks].z = hi ? k01 : r01;
      pa[ks].w = hi ? k23 : r23;
    }

    // ---- O^T += V^T · P^T (V from regs) ----
    __builtin_amdgcn_s_setprio(1);
#pragma unroll
    for (int dt = 0; dt < 2; ++dt) {
#pragma unroll
      for (int ks = 0; ks < 4; ++ks) {
        oacc[dt] = __builtin_amdgcn_mfma_f32_32x32x16_bf16(
            *reinterpret_cast<const bf16x8*>(&vr[dt * 4 + ks]),
            *reinterpret_cast<const bf16x8*>(&pa[ks]), oacc[dt], 0, 0, 0);
      }
    }
    __builtin_amdgcn_s_setprio(0);

    if (pre) {
      asm volatile("s_waitcnt vmcnt(0)" ::: "memory");
      __syncthreads();
    }
    buf ^= 1;
  }

  if (!split) {
    // final: y = O^T / l into q-slot
    float inv = 1.0f / l_run;
#pragma unroll
    for (int dt = 0; dt < 2; ++dt)
#pragma unroll
      for (int u = 0; u < 4; ++u) {
        int d0 = dt * 32 + 8 * u + 4 * hi;
        alignas(8) __bf16 tmp[4];
#pragma unroll
        for (int m = 0; m < 4; ++m) tmp[m] = (__bf16)(oacc[dt][4 * u + m] * inv);
        *reinterpret_cast<uint2*>(qbase + (size_t)q_g * 3072 + d0) =
            *reinterpret_cast<const uint2*>(tmp);
      }
  } else {
    // partial: unnormalized O^T (bf16) into dead v-slot + (m,l)
    int item = ((qc - 16) * 2 + half) * 32 + bh;
    int q_local = w * 32 + l31;
    __bf16* pobase = qkv + (size_t)(item * 4 + (q_local >> 4)) * 3072 + 2048 + (q_local & 15) * 64;
#pragma unroll
    for (int dt = 0; dt < 2; ++dt)
#pragma unroll
      for (int u = 0; u < 4; ++u) {
        int d0 = dt * 32 + 8 * u + 4 * hi;
        alignas(8) __bf16 tmp[4];
#pragma unroll
        for (int m = 0; m < 4; ++m) tmp[m] = (__bf16)oacc[dt][4 * u + m];
        *reinterpret_cast<uint2*>(pobase + d0) = *reinterpret_cast<const uint2*>(tmp);
      }
    if (hi == 0) {
      pml[item * 128 + q_local] = m_run;
      pml[item * 128 + 64 + q_local] = l_run;
    }
  }
}

// ---------------- combine split halves -> final y in q-slot ----------------
__global__ __launch_bounds__(128) void combine_kernel(__bf16* __restrict__ qkv,
                                                      const float* __restrict__ pml) {
  int bid = blockIdx.x;                  // 512: (qc-16)*32 + bh
  int qc = 16 + (bid >> 5), bh = bid & 31;
  int b = bh >> 4, h = bh & 15;
  int t = threadIdx.x;
  int q = t >> 1, dh = (t & 1) * 32;

  int i0 = ((qc - 16) * 2 + 0) * 32 + bh;
  int i1 = i0 + 32;
  float m0 = pml[i0 * 128 + q], l0 = pml[i0 * 128 + 64 + q];
  float m1 = pml[i1 * 128 + q], l1 = pml[i1 * 128 + 64 + q];
  float M = fmaxf(m0, m1);
  float w0 = exp2f(m0 - M), w1 = exp2f(m1 - M);
  float inv = 1.0f / (l0 * w0 + l1 * w1);

  const __bf16* p0 = qkv + (size_t)(i0 * 4 + (q >> 4)) * 3072 + 2048 + (q & 15) * 64 + dh;
  const __bf16* p1 = qkv + (size_t)(i1 * 4 + (q >> 4)) * 3072 + 2048 + (q & 15) * 64 + dh;
  __bf16* yq = qkv + (size_t)(b * SEQ + qc * 64 + q) * 3072 + h * 64 + dh;

#pragma unroll
  for (int c = 0; c < 4; ++c) {
    uint4 ua = *reinterpret_cast<const uint4*>(p0 + c * 8);
    uint4 ub = *reinterpret_cast<const uint4*>(p1 + c * 8);
    const __bf16* va = reinterpret_cast<const __bf16*>(&ua);
    const __bf16* vb = reinterpret_cast<const __bf16*>(&ub);
    alignas(16) __bf16 out[8];
#pragma unroll
    for (int j = 0; j < 8; ++j)
      out[j] = (__bf16)((((float)va[j]) * w0 + ((float)vb[j]) * w1) * inv);
    *reinterpret_cast<uint4*>(yq + c * 8) = *reinterpret_cast<const uint4*>(out);
  }
}

extern "C" void kernel_launch(void* const* d_in, const int* in_sizes, int n_in,
                              void* d_out, int out_size, void* d_ws, size_t ws_size,
                              hipStream_t stream) {
  const float* x = (const float*)d_in[0];
  const float* Wqkv = (const float*)d_in[1];
  const float* Wo = (const float*)d_in[2];
  float* out = (float*)d_out;

  __bf16* ws = (__bf16*)d_ws;
  __bf16* WqkvT = ws;                           // [3072][1024]  6 MB
  __bf16* WoT = WqkvT + 3072 * 1024;            // [1024][1024]  2 MB
  __bf16* qkv = WoT + 1024 * 1024;              // [4096][3072] 24 MB (v-slot reused for partials)
  __bf16* xbf = qkv + (size_t)4096 * 3072;      // [4096][1024]  8 MB (aliased by vtb after gemm1)
  __bf16* vtb = xbf;                            // vt[32][64][2048]
  float* pml = (float*)(xbf + (size_t)4096 * 1024);   // 1024*128 f32 = 512 KB
  float2* sct = (float2*)(pml + 1024 * 128);          // 2048*32 float2 = 512 KB

  build_sct<<<256, 256, 0, stream>>>(sct);
  transpose_cvt<<<dim3(48, 16), 256, 0, stream>>>(Wqkv, WqkvT, 1024, 3072);
  transpose_cvt<<<dim3(16, 16), 256, 0, stream>>>(Wo, WoT, 1024, 1024);
  cvt_fp32_bf16<<<2048, 256, 0, stream>>>(x, xbf);

  gemm_bt_lds<__bf16, 128, true><<<dim3(32, 24), 256, 0, stream>>>(
      xbf, WqkvT, qkv, 4096, 3072, 1024, 1024, 3072, sct);

  transpose_v<<<dim3(32, 32), 256, 0, stream>>>(qkv, vtb);

  attn_kernel<<<1536, 128, 0, stream>>>(qkv, vtb, pml);
  combine_kernel<<<512, 128, 0, stream>>>(qkv, pml);

  gemm_bt_lds<float, 64, false><<<dim3(32, 16), 256, 0, stream>>>(
      qkv, WoT, out, 4096, 1024, 1024, 3072, 1024, sct);
}

// Round 8
// 158.531 us; speedup vs baseline: 1.0950x; 1.0069x over previous
//
#include <hip/hip_runtime.h>

typedef __bf16 bf16x8 __attribute__((ext_vector_type(8)));
typedef float f32x4 __attribute__((ext_vector_type(4)));
typedef float f32x16 __attribute__((ext_vector_type(16)));

constexpr int SEQ = 2048;
constexpr int DMODEL = 1024;

#define GLL(gp, lp)                                                              \
  __builtin_amdgcn_global_load_lds((const __attribute__((address_space(1))) void*)(gp), \
                                   (__attribute__((address_space(3))) void*)(lp), 16, 0, 0)

// ---------------- transpose + fp32->bf16 convert: dst[C][R] = (bf16)src[R][C] ----------------
__global__ __launch_bounds__(256) void transpose_cvt(const float* __restrict__ src,
                                                     __bf16* __restrict__ dst,
                                                     int R, int C) {
  __shared__ __bf16 tile[64][72];
  int c0 = blockIdx.x * 64, r0 = blockIdx.y * 64;
  int t = threadIdx.x;
#pragma unroll
  for (int p = 0; p < 2; ++p) {
    int flat = p * 256 + t;
    int i = flat >> 3;
    int j8 = (flat & 7) * 8;
    const float* sp = &src[(size_t)(r0 + i) * C + c0 + j8];
    float4 f0 = *reinterpret_cast<const float4*>(sp);
    float4 f1 = *reinterpret_cast<const float4*>(sp + 4);
    tile[i][j8 + 0] = (__bf16)f0.x; tile[i][j8 + 1] = (__bf16)f0.y;
    tile[i][j8 + 2] = (__bf16)f0.z; tile[i][j8 + 3] = (__bf16)f0.w;
    tile[i][j8 + 4] = (__bf16)f1.x; tile[i][j8 + 5] = (__bf16)f1.y;
    tile[i][j8 + 6] = (__bf16)f1.z; tile[i][j8 + 7] = (__bf16)f1.w;
  }
  __syncthreads();
#pragma unroll
  for (int p = 0; p < 2; ++p) {
    int flat = p * 256 + t;
    int i = flat >> 3;
    int j8 = (flat & 7) * 8;
    alignas(16) __bf16 tmp[8];
#pragma unroll
    for (int jj = 0; jj < 8; ++jj) tmp[jj] = tile[j8 + jj][i];
    *reinterpret_cast<uint4*>(&dst[(size_t)(c0 + i) * R + r0 + j8]) =
        *reinterpret_cast<const uint4*>(tmp);
  }
}

// ---------------- fp32 -> bf16 bulk convert ----------------
__global__ __launch_bounds__(256) void cvt_fp32_bf16(const float* __restrict__ src,
                                                     __bf16* __restrict__ dst) {
  int i = blockIdx.x * 256 + threadIdx.x;
  const float* sp = src + (size_t)i * 8;
  float4 f0 = *reinterpret_cast<const float4*>(sp);
  float4 f1 = *reinterpret_cast<const float4*>(sp + 4);
  alignas(16) __bf16 tmp[8];
  tmp[0] = (__bf16)f0.x; tmp[1] = (__bf16)f0.y; tmp[2] = (__bf16)f0.z; tmp[3] = (__bf16)f0.w;
  tmp[4] = (__bf16)f1.x; tmp[5] = (__bf16)f1.y; tmp[6] = (__bf16)f1.z; tmp[7] = (__bf16)f1.w;
  *reinterpret_cast<uint4*>(dst + (size_t)i * 8) = *reinterpret_cast<const uint4*>(tmp);
}

// ---------------- sincos table: sct[t][j] = (cos, sin)(t * 10000^(-j/32)) ----------------
__global__ __launch_bounds__(256) void build_sct(float2* __restrict__ sct) {
  int i = blockIdx.x * 256 + threadIdx.x;  // 65536
  int t = i >> 5, j = i & 31;
  float theta = exp2f(-(float)j * 0.41524101186092953f);
  float s, c;
  __sincosf((float)t * theta, &s, &c);
  sct[i] = make_float2(c, s);
}

// ---------------- GEMM (m97 structure): C[M][N] = A[M][K] * BT[N][K]^T ----------------
// MODE 0: plain C write. MODE 1: RoPE epilogue (q scaled by 0.125*log2e), C write.
// MODE 2: v-block; writes V^T directly to vt[bh][d][s] via LDS re-transpose (no C write).
template <typename CT, int BN, int MODE>
__global__ __launch_bounds__(256) void gemm_bt_lds(const __bf16* __restrict__ A,
                                                   const __bf16* __restrict__ BT,
                                                   CT* __restrict__ C,
                                                   int M, int N, int K, int lda, int ldc,
                                                   const float2* __restrict__ sct,
                                                   __bf16* __restrict__ vt) {
  constexpr int MF = (BN == 128) ? 4 : 2;
  __shared__ __align__(16) __bf16 A_lds[128][64];
  __shared__ __align__(16) __bf16 B_lds[BN][64];
  int tid = threadIdx.x;
  int lane = tid & 63, w = tid >> 6;
  int g = lane >> 4, l15 = lane & 15;
  int wr = (BN == 128) ? (w >> 1) : w;
  int wc = (BN == 128) ? (w & 1) : 0;
  int m0 = blockIdx.x * 128;
  int n0 = (MODE == 2) ? (2048 + blockIdx.y * BN) : (blockIdx.y * BN);
  int srow = lane >> 3, scol = (lane & 7) * 8;

  const __bf16* ag = A + (size_t)(m0 + w * 32 + srow) * lda + scol;
  const __bf16* bg = BT + (size_t)(n0 + w * (BN / 4) + srow) * K + scol;

  f32x4 acc[MF][4] = {};

  for (int k0 = 0; k0 < K; k0 += 64) {
    __syncthreads();
#pragma unroll
    for (int i = 0; i < 4; ++i)
      GLL(ag + (size_t)(i * 8) * lda + k0, &A_lds[w * 32 + i * 8][0]);
#pragma unroll
    for (int i = 0; i < BN / 32; ++i)
      GLL(bg + (size_t)(i * 8) * K + k0, &B_lds[w * (BN / 4) + i * 8][0]);
    __syncthreads();
#pragma unroll
    for (int kk = 0; kk < 2; ++kk) {
      bf16x8 a[MF], bb[4];
#pragma unroll
      for (int m = 0; m < MF; ++m)
        a[m] = *reinterpret_cast<const bf16x8*>(&A_lds[wr * (MF * 16) + m * 16 + l15][kk * 32 + g * 8]);
#pragma unroll
      for (int n = 0; n < 4; ++n)
        bb[n] = *reinterpret_cast<const bf16x8*>(&B_lds[wc * 64 + n * 16 + l15][kk * 32 + g * 8]);
#pragma unroll
      for (int m = 0; m < MF; ++m)
#pragma unroll
        for (int n = 0; n < 4; ++n)
          acc[m][n] = __builtin_amdgcn_mfma_f32_16x16x32_bf16(a[m], bb[n], acc[m][n], 0, 0, 0);
    }
  }

  if constexpr (MODE == 1) {
    // wave's 64-col span = exactly one head; d = n*16+l15; pairs (n, n+2) <-> (d, d+32)
    bool isq = (n0 < 1024);
    float sc = isq ? 0.18033688011112042f : 1.0f;  // 0.125 * log2(e) for q (exp2 softmax)
#pragma unroll
    for (int m = 0; m < MF; ++m)
#pragma unroll
      for (int r = 0; r < 4; ++r) {
        int row = m0 + wr * (MF * 16) + m * 16 + 4 * g + r;
        int t = row & (SEQ - 1);
#pragma unroll
        for (int n = 0; n < 2; ++n) {
          int j = n * 16 + l15;  // d in 0..31
          float2 cs = sct[(t << 5) + j];
          float x1 = acc[m][n][r], x2 = acc[m][n + 2][r];
          acc[m][n][r]     = (x1 * cs.x - x2 * cs.y) * sc;
          acc[m][n + 2][r] = (x1 * cs.y + x2 * cs.x) * sc;
        }
      }
  }

  if constexpr (MODE == 2) {
    __shared__ __bf16 T_lds[128][72];
    int b = m0 >> 11;
    int s_base = m0 & (SEQ - 1);
#pragma unroll
    for (int half = 0; half < 2; ++half) {
      __syncthreads();
      if (wc == half) {
#pragma unroll
        for (int m = 0; m < MF; ++m)
#pragma unroll
          for (int n = 0; n < 4; ++n)
#pragma unroll
            for (int r = 0; r < 4; ++r)
              T_lds[wr * 64 + m * 16 + 4 * g + r][n * 16 + l15] = (__bf16)acc[m][n][r];
      }
      __syncthreads();
      int head = ((n0 - 2048) >> 6) + half;
      int bh = b * 16 + head;
      int d = tid >> 2;
      int s8 = (tid & 3) * 32;
      __bf16* dst = vt + (size_t)bh * 64 * SEQ + (size_t)d * SEQ + s_base + s8;
#pragma unroll
      for (int j = 0; j < 4; ++j) {
        alignas(16) __bf16 tmp[8];
#pragma unroll
        for (int e = 0; e < 8; ++e) tmp[e] = T_lds[s8 + j * 8 + e][d];
        *reinterpret_cast<uint4*>(dst + j * 8) = *reinterpret_cast<const uint4*>(tmp);
      }
    }
    return;
  }

#pragma unroll
  for (int m = 0; m < MF; ++m)
#pragma unroll
    for (int n = 0; n < 4; ++n)
#pragma unroll
      for (int r = 0; r < 4; ++r) {
        int row = m0 + wr * (MF * 16) + m * 16 + 4 * g + r;
        int col = n0 + wc * 64 + n * 16 + l15;
        C[(size_t)row * ldc + col] = (CT)acc[m][n][r];
      }
}

__device__ inline uint32_t pkbf(float a, float b) {
  union { __bf16 h[2]; uint32_t u; } z;
  z.h[0] = (__bf16)a; z.h[1] = (__bf16)b;
  return z.u;
}

// ---------------- causal flash attention with split-K ----------------
// 1536 items: it<32 -> split halves of qc=31-(it>>1); it>=32 -> single qc=47-it.
// 2 waves x 32 q-rows. K in LDS (dbuf, swizzled, GLL); V^T read global->reg FIRST
// (so the pre-PV vmcnt wait keeps next-tile staging in flight).
__global__ __launch_bounds__(128, 3) void attn_kernel(__bf16* __restrict__ qkv,
                                                      const __bf16* __restrict__ vt,
                                                      float* __restrict__ pml) {
  __shared__ __align__(16) __bf16 K_lds[2][64][64];

  int tid = threadIdx.x;
  int w = tid >> 6, lane = tid & 63;
  int l31 = lane & 31, hi = lane >> 5;
  int bid = blockIdx.x;
  int it = bid >> 5, bh = bid & 31;
  int b = bh >> 4, h = bh & 15;

  int qc, kv0, kv1, half;
  bool split;
  if (it < 32) {
    qc = 31 - (it >> 1);
    half = it & 1;
    int NTf = qc + 1;
    int hs = (NTf + 1) >> 1;
    kv0 = half ? hs : 0;
    kv1 = half ? NTf : hs;
    split = true;
  } else {
    qc = 47 - it;
    kv0 = 0;
    kv1 = qc + 1;
    split = false;
    half = 0;
  }
  int NT = kv1 - kv0;

  __bf16* qbase = qkv + (size_t)b * SEQ * 3072 + h * 64;
  const __bf16* kbase = qbase + 1024;
  const __bf16* vtb = vt + (size_t)bh * 64 * SEQ;

  int q_g = qc * 64 + w * 32 + l31;  // lane's global q row (within b)

  // K staging coords (pre-swizzled source)
  int r8 = lane >> 3;
  int cxe = 8 * ((lane & 7) ^ r8);

  auto STAGE = [&](int bufv, int t) {
#pragma unroll
    for (int i = 0; i < 4; ++i) {
      int R = w * 32 + i * 8;
      GLL(kbase + (size_t)(t * 64 + R + r8) * 3072 + cxe, &K_lds[bufv][R][0]);
    }
  };

  // Q fragments
  bf16x8 qf[4];
#pragma unroll
  for (int ds = 0; ds < 4; ++ds)
    qf[ds] = *reinterpret_cast<const bf16x8*>(qbase + (size_t)q_g * 3072 + ds * 16 + 8 * hi);

  f32x16 oacc[2] = {};
  float m_run = -1e30f, l_run = 0.f;

  STAGE(0, kv0);
  __syncthreads();

  int buf = 0;
  for (int jb = 0; jb < NT; ++jb) {
    int kt_g = kv0 + jb;
    bool pre = (jb + 1 < NT);

    // ---- V^T prefetch FIRST (global->reg) so pre-PV wait is vmcnt(8), not 0 ----
    uint4 vr[8];
#pragma unroll
    for (int dt = 0; dt < 2; ++dt)
#pragma unroll
      for (int ks = 0; ks < 4; ++ks)
        vr[dt * 4 + ks] = *reinterpret_cast<const uint4*>(
            vtb + (size_t)(dt * 32 + l31) * SEQ + kt_g * 64 + ks * 16 + 8 * hi);
    __builtin_amdgcn_sched_barrier(0);

    if (pre) STAGE(buf ^ 1, kt_g + 1);

    // ---- S^T = K · Q^T ----
    f32x16 sacc[2] = {};
    __builtin_amdgcn_s_setprio(1);
#pragma unroll
    for (int kt = 0; kt < 2; ++kt) {
#pragma unroll
      for (int ds = 0; ds < 4; ++ds) {
        bf16x8 kf = *reinterpret_cast<const bf16x8*>(
            &K_lds[buf][kt * 32 + l31][(ds * 16 + 8 * hi) ^ ((l31 & 7) * 8)]);
        sacc[kt] = __builtin_amdgcn_mfma_f32_32x32x16_bf16(kf, qf[ds], sacc[kt], 0, 0, 0);
      }
    }
    __builtin_amdgcn_s_setprio(0);

    // ---- causal mask on the diagonal tile ----
    if (kt_g == qc) {
#pragma unroll
      for (int kt = 0; kt < 2; ++kt)
#pragma unroll
        for (int r = 0; r < 16; ++r) {
          int k_g = kt_g * 64 + kt * 32 + (r & 3) + 8 * (r >> 2) + 4 * hi;
          if (k_g > q_g) sacc[kt][r] = -1e30f;
        }
    }

    // ---- row max: elementwise + tree + partner swap ----
    float mx[8];
#pragma unroll
    for (int r = 0; r < 8; ++r)
      mx[r] = fmaxf(fmaxf(sacc[0][r], sacc[0][r + 8]), fmaxf(sacc[1][r], sacc[1][r + 8]));
    float m01 = fmaxf(fmaxf(mx[0], mx[1]), fmaxf(mx[2], mx[3]));
    float m23 = fmaxf(fmaxf(mx[4], mx[5]), fmaxf(mx[6], mx[7]));
    float tm = fmaxf(m01, m23);
    tm = fmaxf(tm, __shfl_xor(tm, 32));

    // ---- T13 defer-max ----
    float m_new, alpha;
    if (__all(tm - m_run <= 8.f)) {
      m_new = m_run;
      alpha = 1.f;
    } else {
      m_new = fmaxf(m_run, tm);
      alpha = exp2f(m_run - m_new);
      m_run = m_new;
#pragma unroll
      for (int dt = 0; dt < 2; ++dt)
#pragma unroll
        for (int r = 0; r < 16; ++r) oacc[dt][r] *= alpha;
    }

    // ---- p = exp2(s - m); 4 parallel sum chains ----
    float s0 = 0.f, s1 = 0.f, s2 = 0.f, s3 = 0.f;
#pragma unroll
    for (int kt = 0; kt < 2; ++kt) {
#pragma unroll
      for (int r = 0; r < 16; r += 4) {
        float p0 = exp2f(sacc[kt][r + 0] - m_new);
        float p1 = exp2f(sacc[kt][r + 1] - m_new);
        float p2 = exp2f(sacc[kt][r + 2] - m_new);
        float p3 = exp2f(sacc[kt][r + 3] - m_new);
        sacc[kt][r + 0] = p0; sacc[kt][r + 1] = p1;
        sacc[kt][r + 2] = p2; sacc[kt][r + 3] = p3;
        s0 += p0; s1 += p1; s2 += p2; s3 += p3;
      }
    }
    float sum = (s0 + s1) + (s2 + s3);
    sum += __shfl_xor(sum, 32);
    l_run = l_run * alpha + sum;

    // ---- build P fragments ----
    uint4 pa[4];
#pragma unroll
    for (int ks = 0; ks < 4; ++ks) {
      int v0 = 2 * ks, v1 = v0 + 1;
      int t0 = v0 >> 2, rb0 = 4 * (v0 & 3);
      int t1 = v1 >> 2, rb1 = 4 * (v1 & 3);
      uint32_t a01, a23, b01, b23;
      if (t0 == 0) { a01 = pkbf(sacc[0][rb0 + 0], sacc[0][rb0 + 1]);
                     a23 = pkbf(sacc[0][rb0 + 2], sacc[0][rb0 + 3]); }
      else         { a01 = pkbf(sacc[1][rb0 + 0], sacc[1][rb0 + 1]);
                     a23 = pkbf(sacc[1][rb0 + 2], sacc[1][rb0 + 3]); }
      if (t1 == 0) { b01 = pkbf(sacc[0][rb1 + 0], sacc[0][rb1 + 1]);
                     b23 = pkbf(sacc[0][rb1 + 2], sacc[0][rb1 + 3]); }
      else         { b01 = pkbf(sacc[1][rb1 + 0], sacc[1][rb1 + 1]);
                     b23 = pkbf(sacc[1][rb1 + 2], sacc[1][rb1 + 3]); }
      uint32_t t01 = hi ? a01 : b01;
      uint32_t t23 = hi ? a23 : b23;
      uint32_t r01 = __shfl_xor(t01, 32);
      uint32_t r23 = __shfl_xor(t23, 32);
      uint32_t k01 = hi ? b01 : a01;
      uint32_t k23 = hi ? b23 : a23;
      pa[ks].x = hi ? r01 : k01;
      pa[ks].y = hi ? r23 : k23;
      pa[ks].z = hi ? k01 : r01;
      pa[ks].w = hi ? k23 : r23;
    }

    // ---- O^T += V^T · P^T (V from regs) ----
    __builtin_amdgcn_s_setprio(1);
#pragma unroll
    for (int dt = 0; dt < 2; ++dt) {
#pragma unroll
      for (int ks = 0; ks < 4; ++ks) {
        oacc[dt] = __builtin_amdgcn_mfma_f32_32x32x16_bf16(
            *reinterpret_cast<const bf16x8*>(&vr[dt * 4 + ks]),
            *reinterpret_cast<const bf16x8*>(&pa[ks]), oacc[dt], 0, 0, 0);
      }
    }
    __builtin_amdgcn_s_setprio(0);

    if (pre) {
      asm volatile("s_waitcnt vmcnt(0)" ::: "memory");
      __syncthreads();
    }
    buf ^= 1;
  }

  if (!split) {
    // final: y = O^T / l into q-slot
    float inv = 1.0f / l_run;
#pragma unroll
    for (int dt = 0; dt < 2; ++dt)
#pragma unroll
      for (int u = 0; u < 4; ++u) {
        int d0 = dt * 32 + 8 * u + 4 * hi;
        alignas(8) __bf16 tmp[4];
#pragma unroll
        for (int m = 0; m < 4; ++m) tmp[m] = (__bf16)(oacc[dt][4 * u + m] * inv);
        *reinterpret_cast<uint2*>(qbase + (size_t)q_g * 3072 + d0) =
            *reinterpret_cast<const uint2*>(tmp);
      }
  } else {
    // partial: unnormalized O^T (bf16) into dead v-slot + (m,l)
    int item = ((qc - 16) * 2 + half) * 32 + bh;
    int q_local = w * 32 + l31;
    __bf16* pobase = qkv + (size_t)(item * 4 + (q_local >> 4)) * 3072 + 2048 + (q_local & 15) * 64;
#pragma unroll
    for (int dt = 0; dt < 2; ++dt)
#pragma unroll
      for (int u = 0; u < 4; ++u) {
        int d0 = dt * 32 + 8 * u + 4 * hi;
        alignas(8) __bf16 tmp[4];
#pragma unroll
        for (int m = 0; m < 4; ++m) tmp[m] = (__bf16)oacc[dt][4 * u + m];
        *reinterpret_cast<uint2*>(pobase + d0) = *reinterpret_cast<const uint2*>(tmp);
      }
    if (hi == 0) {
      pml[item * 128 + q_local] = m_run;
      pml[item * 128 + 64 + q_local] = l_run;
    }
  }
}

// ---------------- combine split halves -> final y in q-slot ----------------
__global__ __launch_bounds__(128) void combine_kernel(__bf16* __restrict__ qkv,
                                                      const float* __restrict__ pml) {
  int bid = blockIdx.x;                  // 512: (qc-16)*32 + bh
  int qc = 16 + (bid >> 5), bh = bid & 31;
  int b = bh >> 4, h = bh & 15;
  int t = threadIdx.x;
  int q = t >> 1, dh = (t & 1) * 32;

  int i0 = ((qc - 16) * 2 + 0) * 32 + bh;
  int i1 = i0 + 32;
  float m0 = pml[i0 * 128 + q], l0 = pml[i0 * 128 + 64 + q];
  float m1 = pml[i1 * 128 + q], l1 = pml[i1 * 128 + 64 + q];
  float M = fmaxf(m0, m1);
  float w0 = exp2f(m0 - M), w1 = exp2f(m1 - M);
  float inv = 1.0f / (l0 * w0 + l1 * w1);

  const __bf16* p0 = qkv + (size_t)(i0 * 4 + (q >> 4)) * 3072 + 2048 + (q & 15) * 64 + dh;
  const __bf16* p1 = qkv + (size_t)(i1 * 4 + (q >> 4)) * 3072 + 2048 + (q & 15) * 64 + dh;
  __bf16* yq = qkv + (size_t)(b * SEQ + qc * 64 + q) * 3072 + h * 64 + dh;

#pragma unroll
  for (int c = 0; c < 4; ++c) {
    uint4 ua = *reinterpret_cast<const uint4*>(p0 + c * 8);
    uint4 ub = *reinterpret_cast<const uint4*>(p1 + c * 8);
    const __bf16* va = reinterpret_cast<const __bf16*>(&ua);
    const __bf16* vb = reinterpret_cast<const __bf16*>(&ub);
    alignas(16) __bf16 out[8];
#pragma unroll
    for (int j = 0; j < 8; ++j)
      out[j] = (__bf16)((((float)va[j]) * w0 + ((float)vb[j]) * w1) * inv);
    *reinterpret_cast<uint4*>(yq + c * 8) = *reinterpret_cast<const uint4*>(out);
  }
}

extern "C" void kernel_launch(void* const* d_in, const int* in_sizes, int n_in,
                              void* d_out, int out_size, void* d_ws, size_t ws_size,
                              hipStream_t stream) {
  const float* x = (const float*)d_in[0];
  const float* Wqkv = (const float*)d_in[1];
  const float* Wo = (const float*)d_in[2];
  float* out = (float*)d_out;

  __bf16* ws = (__bf16*)d_ws;
  __bf16* WqkvT = ws;                           // [3072][1024]  6 MB
  __bf16* WoT = WqkvT + 3072 * 1024;            // [1024][1024]  2 MB
  __bf16* qkv = WoT + 1024 * 1024;              // [4096][3072] 24 MB (v-slot = partial scratch)
  __bf16* xbf = qkv + (size_t)4096 * 3072;      // [4096][1024]  8 MB input bf16
  __bf16* vtb = xbf + (size_t)4096 * 1024;      // vt[32][64][2048] 8 MB
  float* pml = (float*)(vtb + (size_t)32 * 64 * SEQ);  // 1024*128 f32 = 512 KB
  float2* sct = (float2*)(pml + 1024 * 128);           // 2048*32 float2 = 512 KB

  build_sct<<<256, 256, 0, stream>>>(sct);
  transpose_cvt<<<dim3(48, 16), 256, 0, stream>>>(Wqkv, WqkvT, 1024, 3072);
  transpose_cvt<<<dim3(16, 16), 256, 0, stream>>>(Wo, WoT, 1024, 1024);
  cvt_fp32_bf16<<<2048, 256, 0, stream>>>(x, xbf);

  // qk columns (0..2047) with RoPE epilogue
  gemm_bt_lds<__bf16, 128, 1><<<dim3(32, 16), 256, 0, stream>>>(
      xbf, WqkvT, qkv, 4096, 3072, 1024, 1024, 3072, sct, nullptr);
  // v columns (2048..3071) -> vt directly
  gemm_bt_lds<__bf16, 128, 2><<<dim3(32, 8), 256, 0, stream>>>(
      xbf, WqkvT, qkv, 4096, 3072, 1024, 1024, 3072, sct, vtb);

  attn_kernel<<<1536, 128, 0, stream>>>(qkv, vtb, pml);
  combine_kernel<<<512, 128, 0, stream>>>(qkv, pml);

  gemm_bt_lds<float, 64, 0><<<dim3(32, 16), 256, 0, stream>>>(
      qkv, WoT, out, 4096, 1024, 1024, 3072, 1024, sct, nullptr);
}